// Round 5
// baseline (374.874 us; speedup 1.0000x reference)
//
#include <hip/hip_runtime.h>

// ---------------------------------------------------------------------------
// 2-layer GCN: z = A_hat (relu(A_hat (X W1) + b1)) W2 + b2
// CSR-by-dst built once; transform-then-aggregate for both layers.
// R5: CSR fill split into bin_scatter (dst>>4 bins, bin regions derived from
// offs -- no extra scan) + fill_from_binned. Kills the 8x write-line
// amplification of the old random 8B scatter. Temp binned buffer aliases h.
// ---------------------------------------------------------------------------

#define KDIM 128
#define BIN_SHIFT 4

typedef unsigned int uint;
typedef unsigned short ushort;
typedef __attribute__((ext_vector_type(8))) short bf16x8;
typedef __attribute__((ext_vector_type(4))) float f32x4;

__device__ inline ushort f2bf(float f) {              // RNE f32 -> bf16
    uint u = __float_as_uint(f);
    return (ushort)((u + 0x7fffu + ((u >> 16) & 1u)) >> 16);
}

__global__ void init_counts(int* counts, int* cursor, int n) {
    int i = blockIdx.x * blockDim.x + threadIdx.x;
    int stride = gridDim.x * blockDim.x;
    for (; i < n; i += stride) { counts[i] = 0; cursor[i] = 0; }
}

__global__ void count_kernel(const int* __restrict__ dst, int* __restrict__ counts, int e) {
    int i = blockIdx.x * blockDim.x + threadIdx.x;
    int stride = gridDim.x * blockDim.x;
    for (; i < e; i += stride) atomicAdd(&counts[dst[i]], 1);
}

__global__ void dinv_kernel(const int* __restrict__ counts, float* __restrict__ dinv, int n) {
    int i = blockIdx.x * blockDim.x + threadIdx.x;
    int stride = gridDim.x * blockDim.x;
    for (; i < n; i += stride) dinv[i] = rsqrtf((float)(counts[i] + 1));
}

// --- 3-kernel exclusive scan over counts -> offsets -------------------------
__global__ void scan_partial(const int* __restrict__ counts, int* __restrict__ local,
                             int* __restrict__ bsums, int n) {
    __shared__ int ld[1024];
    __shared__ int ts[256];
    const int t = threadIdx.x;
    const int base = blockIdx.x * 1024;
    for (int j = t; j < 1024; j += 256) ld[j] = (base + j < n) ? counts[base + j] : 0;
    __syncthreads();
    int a0 = ld[4*t], a1 = ld[4*t+1], a2 = ld[4*t+2], a3 = ld[4*t+3];
    int sum = a0 + a1 + a2 + a3;
    ts[t] = sum;
    for (int off = 1; off < 256; off <<= 1) {
        __syncthreads();
        int v = (t >= off) ? ts[t - off] : 0;
        __syncthreads();
        ts[t] += v;
    }
    __syncthreads();
    int excl = ts[t] - sum;
    if (base + 4*t + 0 < n) local[base + 4*t + 0] = excl;
    if (base + 4*t + 1 < n) local[base + 4*t + 1] = excl + a0;
    if (base + 4*t + 2 < n) local[base + 4*t + 2] = excl + a0 + a1;
    if (base + 4*t + 3 < n) local[base + 4*t + 3] = excl + a0 + a1 + a2;
    if (t == 255) bsums[blockIdx.x] = ts[255];
}

__global__ void scan_bsums(int* __restrict__ bsums, int nb) {
    __shared__ int ts[256];
    const int t = threadIdx.x;
    int v = (t < nb) ? bsums[t] : 0;
    ts[t] = v;
    for (int off = 1; off < 256; off <<= 1) {
        __syncthreads();
        int u = (t >= off) ? ts[t - off] : 0;
        __syncthreads();
        ts[t] += u;
    }
    __syncthreads();
    if (t < nb) bsums[t] = ts[t] - v;
}

__global__ void scan_add(int* __restrict__ offs, const int* __restrict__ bsums, int n, int e_total) {
    int i = blockIdx.x * blockDim.x + threadIdx.x;
    int stride = gridDim.x * blockDim.x;
    for (; i < n; i += stride) offs[i] += bsums[i >> 10];
    if (blockIdx.x == 0 && threadIdx.x == 0) offs[n] = e_total;
}

// --- binned CSR fill --------------------------------------------------------
__global__ void bin_cursor_init(const int* __restrict__ offs, int* __restrict__ bin_cursor,
                                int nbins, int n) {
    int b = blockIdx.x * blockDim.x + threadIdx.x;
    if (b < nbins) {
        int node = b << BIN_SHIFT;
        if (node > n) node = n;
        bin_cursor[b] = offs[node];
    }
}

// pass C: scatter (src,dst) into bin-contiguous temp. Bin region = exactly
// [offs[16b], offs[16(b+1)}) so writes cluster (one hot line per bin).
__global__ void bin_scatter(const int* __restrict__ src, const int* __restrict__ dst,
                            int* __restrict__ bin_cursor, int2* __restrict__ tmp, int e) {
    int i = blockIdx.x * blockDim.x + threadIdx.x;
    int stride = gridDim.x * blockDim.x;
    for (; i < e; i += stride) {
        int s = src[i], d = dst[i];
        int pos = atomicAdd(&bin_cursor[d >> BIN_SHIFT], 1);
        tmp[pos] = make_int2(s, d);
    }
}

// pass D: coalesced read of binned edges; final scatter confined to each
// bin's ~2KB CSR window (L2-hot). Record = (src, norm).
__global__ void fill_from_binned(const int2* __restrict__ tmp, const int* __restrict__ offs,
                                 int* __restrict__ cursor, const float* __restrict__ dinv,
                                 int2* __restrict__ csr, int e) {
    int i = blockIdx.x * blockDim.x + threadIdx.x;
    int stride = gridDim.x * blockDim.x;
    for (; i < e; i += stride) {
        int2 sd = tmp[i];
        int d = sd.y;
        int pos = offs[d] + atomicAdd(&cursor[d], 1);
        csr[pos] = make_int2(sd.x, __float_as_int(dinv[sd.x] * dinv[d]));
    }
}

// --- pack W1 (f32 [128][128]) into bf16 B-fragment order --------------------
__global__ void packW1_kernel(const float* __restrict__ W1, ushort* __restrict__ W1f) {
    int idx = blockIdx.x * blockDim.x + threadIdx.x;   // 16384 total
    int k = idx >> 7, col = idx & 127;
    int c = col >> 4, lcol = col & 15;
    int t = k >> 5, u = (k >> 3) & 3, j = k & 7;
    int lane = u * 16 + lcol;
    W1f[(size_t)(((c * 4 + t) * 64 + lane) * 8 + j)] = f2bf(W1[idx]);
}

// --- matmul1 via MFMA: xw1b[n x 128] (bf16) = x @ W1 ------------------------
__global__ __launch_bounds__(256)
void mfma1_kernel(const float* __restrict__ x, const ushort* __restrict__ W1f,
                  ushort* __restrict__ outb, int n) {
    __shared__ ushort bsm[16384];                      // 32 KB, frag order
    const int tid = threadIdx.x;
    #pragma unroll
    for (int j = 0; j < 8; ++j)
        ((uint4*)bsm)[tid + j * 256] = ((const uint4*)W1f)[tid + j * 256];

    const int w = tid >> 6;
    const int lane = tid & 63;
    const int r = lane & 15;
    const int u = lane >> 4;
    const int row0 = blockIdx.x * 64 + w * 16;
    int arow = row0 + r; if (arow >= n) arow = n - 1;

    bf16x8 afr[4];
    #pragma unroll
    for (int t = 0; t < 4; ++t) {
        const float* px = &x[(size_t)arow * 128 + t * 32 + u * 8];
        f32x4 v0 = *(const f32x4*)px;
        f32x4 v1 = *(const f32x4*)(px + 4);
        bf16x8 a;
        a[0] = (short)f2bf(v0[0]); a[1] = (short)f2bf(v0[1]);
        a[2] = (short)f2bf(v0[2]); a[3] = (short)f2bf(v0[3]);
        a[4] = (short)f2bf(v1[0]); a[5] = (short)f2bf(v1[1]);
        a[6] = (short)f2bf(v1[2]); a[7] = (short)f2bf(v1[3]);
        afr[t] = a;
    }
    __syncthreads();

    f32x4 acc[8];
    #pragma unroll
    for (int c = 0; c < 8; ++c) acc[c] = (f32x4){0.f, 0.f, 0.f, 0.f};

    #pragma unroll
    for (int c = 0; c < 8; ++c) {
        #pragma unroll
        for (int t = 0; t < 4; ++t) {
            bf16x8 b = *(const bf16x8*)&bsm[(size_t)(((c * 4 + t) * 64 + lane) * 8)];
            acc[c] = __builtin_amdgcn_mfma_f32_16x16x32_bf16(afr[t], b, acc[c], 0, 0, 0);
        }
    }

    #pragma unroll
    for (int c = 0; c < 8; ++c) {
        #pragma unroll
        for (int rr = 0; rr < 4; ++rr) {
            int row = row0 + u * 4 + rr;
            if (row < n) outb[(size_t)row * 128 + c * 16 + r] = f2bf(acc[c][rr]);
        }
    }
}

// --- generic small matmul (layer 2): out[n x DOUT] = x[n x 128] @ W ---------
template<int ROWS, int DOUT>
__global__ __launch_bounds__((ROWS/4)*(DOUT/4))
void matmul_kernel(const float* __restrict__ x, const float* __restrict__ W,
                   float* __restrict__ out, int n) {
    constexpr int K = KDIM;
    constexpr int TPB = (ROWS/4) * (DOUT/4);
    __shared__ float xs[ROWS][K];
    __shared__ float ws[K][DOUT];
    const int tid = threadIdx.x;
    const int row0 = blockIdx.x * ROWS;

    for (int idx = tid; idx < K*DOUT/4; idx += TPB)
        ((float4*)ws)[idx] = ((const float4*)W)[idx];
    for (int idx = tid; idx < ROWS*K/4; idx += TPB) {
        int r = idx / (K/4);
        int row = row0 + r;
        float4 v = (row < n) ? ((const float4*)x)[(size_t)row*(K/4) + (idx % (K/4))]
                             : make_float4(0.f, 0.f, 0.f, 0.f);
        ((float4*)xs)[idx] = v;
    }
    __syncthreads();

    const int tc = tid % (DOUT/4);
    const int tr = tid / (DOUT/4);
    float acc[4][4] = {};
    #pragma unroll 4
    for (int k = 0; k < K; k += 4) {
        float xa[4][4], wb[4][4];
        #pragma unroll
        for (int r = 0; r < 4; ++r) {
            float4 v = *(const float4*)&xs[tr*4 + r][k];
            xa[r][0] = v.x; xa[r][1] = v.y; xa[r][2] = v.z; xa[r][3] = v.w;
        }
        #pragma unroll
        for (int kk = 0; kk < 4; ++kk) {
            float4 v = *(const float4*)&ws[k + kk][tc*4];
            wb[kk][0] = v.x; wb[kk][1] = v.y; wb[kk][2] = v.z; wb[kk][3] = v.w;
        }
        #pragma unroll
        for (int r = 0; r < 4; ++r)
            #pragma unroll
            for (int kk = 0; kk < 4; ++kk)
                #pragma unroll
                for (int c = 0; c < 4; ++c)
                    acc[r][c] += xa[r][kk] * wb[kk][c];
    }
    #pragma unroll
    for (int r = 0; r < 4; ++r) {
        int row = row0 + tr*4 + r;
        if (row < n) {
            float4 v = make_float4(acc[r][0], acc[r][1], acc[r][2], acc[r][3]);
            *(float4*)&out[(size_t)row*DOUT + tc*4] = v;
        }
    }
}

// --- aggregation, D=128 over bf16 rows: one wave per node -------------------
__device__ inline void bf2_fma(uint u, float nr, float& a0, float& a1) {
    a0 += __uint_as_float(u << 16) * nr;
    a1 += __uint_as_float(u & 0xffff0000u) * nr;
}

__global__ __launch_bounds__(256)
void agg128_kernel(const ushort* __restrict__ xwb, const int* __restrict__ offs,
                   const int2* __restrict__ csr, const float* __restrict__ dinv,
                   const float* __restrict__ bias, float* __restrict__ out,
                   int n, int do_relu) {
    const int w = threadIdx.x >> 6;
    const int i = blockIdx.x * 4 + w;
    if (i >= n) return;
    const int lane = threadIdx.x & 63;
    const int g = lane >> 4;
    const int q = lane & 15;

    float acc[8] = {};
    const int e0 = offs[i], e1 = offs[i + 1];
    int e = e0 + g;
    for (; e + 4 < e1; e += 8) {
        int2 p0 = csr[e];
        int2 p1 = csr[e + 4];
        uint4 u0 = *(const uint4*)&xwb[(size_t)p0.x * 128 + q * 8];
        uint4 u1 = *(const uint4*)&xwb[(size_t)p1.x * 128 + q * 8];
        float n0 = __int_as_float(p0.y);
        float n1 = __int_as_float(p1.y);
        bf2_fma(u0.x, n0, acc[0], acc[1]);
        bf2_fma(u0.y, n0, acc[2], acc[3]);
        bf2_fma(u0.z, n0, acc[4], acc[5]);
        bf2_fma(u0.w, n0, acc[6], acc[7]);
        bf2_fma(u1.x, n1, acc[0], acc[1]);
        bf2_fma(u1.y, n1, acc[2], acc[3]);
        bf2_fma(u1.z, n1, acc[4], acc[5]);
        bf2_fma(u1.w, n1, acc[6], acc[7]);
    }
    if (e < e1) {
        int2 p = csr[e];
        uint4 u = *(const uint4*)&xwb[(size_t)p.x * 128 + q * 8];
        float nr = __int_as_float(p.y);
        bf2_fma(u.x, nr, acc[0], acc[1]);
        bf2_fma(u.y, nr, acc[2], acc[3]);
        bf2_fma(u.z, nr, acc[4], acc[5]);
        bf2_fma(u.w, nr, acc[6], acc[7]);
    }
    #pragma unroll
    for (int j = 0; j < 8; ++j) {
        acc[j] += __shfl_xor(acc[j], 16, 64);
        acc[j] += __shfl_xor(acc[j], 32, 64);
    }

    if (g == 0) {
        const float di = dinv[i];
        const float s = di * di;
        uint4 su = *(const uint4*)&xwb[(size_t)i * 128 + q * 8];
        bf2_fma(su.x, s, acc[0], acc[1]);
        bf2_fma(su.y, s, acc[2], acc[3]);
        bf2_fma(su.z, s, acc[4], acc[5]);
        bf2_fma(su.w, s, acc[6], acc[7]);
        const float4 b0 = *(const float4*)&bias[q * 8];
        const float4 b1 = *(const float4*)&bias[q * 8 + 4];
        float4 r0, r1;
        r0.x = acc[0] + b0.x; r0.y = acc[1] + b0.y; r0.z = acc[2] + b0.z; r0.w = acc[3] + b0.w;
        r1.x = acc[4] + b1.x; r1.y = acc[5] + b1.y; r1.z = acc[6] + b1.z; r1.w = acc[7] + b1.w;
        if (do_relu) {
            r0.x = fmaxf(r0.x, 0.f); r0.y = fmaxf(r0.y, 0.f);
            r0.z = fmaxf(r0.z, 0.f); r0.w = fmaxf(r0.w, 0.f);
            r1.x = fmaxf(r1.x, 0.f); r1.y = fmaxf(r1.y, 0.f);
            r1.z = fmaxf(r1.z, 0.f); r1.w = fmaxf(r1.w, 0.f);
        }
        *(float4*)&out[(size_t)i * 128 + q * 8] = r0;
        *(float4*)&out[(size_t)i * 128 + q * 8 + 4] = r1;
    }
}

// --- aggregation, D=32 (f32): one wave per node, 8 edges in parallel --------
__global__ __launch_bounds__(256)
void agg32_kernel(const float* __restrict__ xw, const int* __restrict__ offs,
                  const int2* __restrict__ csr, const float* __restrict__ dinv,
                  const float* __restrict__ bias, float* __restrict__ out, int n) {
    const int w = threadIdx.x >> 6;
    const int i = blockIdx.x * 4 + w;
    if (i >= n) return;
    const int lane = threadIdx.x & 63;
    const int g = lane >> 3;
    const int q = lane & 7;

    float4 acc = make_float4(0.f, 0.f, 0.f, 0.f);
    const int e0 = offs[i], e1 = offs[i + 1];
    int e = e0 + g;
    for (; e + 8 < e1; e += 16) {
        int2 p0 = csr[e];
        int2 p1 = csr[e + 8];
        const float4 v0 = *(const float4*)&xw[(size_t)p0.x * 32 + q * 4];
        const float4 v1 = *(const float4*)&xw[(size_t)p1.x * 32 + q * 4];
        const float n0 = __int_as_float(p0.y);
        const float n1 = __int_as_float(p1.y);
        acc.x += v0.x * n0; acc.y += v0.y * n0; acc.z += v0.z * n0; acc.w += v0.w * n0;
        acc.x += v1.x * n1; acc.y += v1.y * n1; acc.z += v1.z * n1; acc.w += v1.w * n1;
    }
    if (e < e1) {
        int2 p = csr[e];
        const float4 v = *(const float4*)&xw[(size_t)p.x * 32 + q * 4];
        const float nr = __int_as_float(p.y);
        acc.x += v.x * nr; acc.y += v.y * nr; acc.z += v.z * nr; acc.w += v.w * nr;
    }
    #pragma unroll
    for (int m = 8; m <= 32; m <<= 1) {
        acc.x += __shfl_xor(acc.x, m, 64);
        acc.y += __shfl_xor(acc.y, m, 64);
        acc.z += __shfl_xor(acc.z, m, 64);
        acc.w += __shfl_xor(acc.w, m, 64);
    }

    if (g == 0) {
        const float di = dinv[i];
        const float s = di * di;
        const float4 sv = *(const float4*)&xw[(size_t)i * 32 + q * 4];
        const float4 b  = *(const float4*)&bias[q * 4];
        float4 r;
        r.x = acc.x + sv.x * s + b.x;
        r.y = acc.y + sv.y * s + b.y;
        r.z = acc.z + sv.z * s + b.z;
        r.w = acc.w + sv.w * s + b.w;
        *(float4*)&out[(size_t)i * 32 + q * 4] = r;
    }
}

extern "C" void kernel_launch(void* const* d_in, const int* in_sizes, int n_in,
                              void* d_out, int out_size, void* d_ws, size_t ws_size,
                              hipStream_t stream) {
    const int n = in_sizes[0] / KDIM;      // 100000
    const int e = in_sizes[1] / 2;         // 1600000

    const float* x  = (const float*)d_in[0];
    const int*   ei = (const int*)d_in[1];
    const int*   src = ei;
    const int*   dst = ei + e;
    const float* W1 = (const float*)d_in[2];
    const float* b1 = (const float*)d_in[3];
    const float* W2 = (const float*)d_in[4];
    const float* b2 = (const float*)d_in[5];
    float* out = (float*)d_out;

    // workspace carve (256B aligned)
    char* p = (char*)d_ws;
    auto alloc = [&](size_t bytes) { char* q = p; p += (bytes + 255) & ~(size_t)255; return q; };
    const int nbins = (n + (1 << BIN_SHIFT) - 1) >> BIN_SHIFT;   // 6250
    float*  dinv   = (float*)alloc((size_t)n * 4);
    int*    counts = (int*)  alloc((size_t)n * 4);
    int*    cursor = (int*)  alloc((size_t)n * 4);
    int*    offs   = (int*)  alloc((size_t)(n + 1) * 4);
    int*    bsums  = (int*)  alloc(1024 * 4);
    int*    bin_cursor = (int*)alloc((size_t)nbins * 4);
    int2*   csr    = (int2*) alloc((size_t)e * 8);
    ushort* W1f    = (ushort*)alloc((size_t)128 * 128 * 2);
    ushort* xw1b   = (ushort*)alloc((size_t)n * 128 * 2);
    float*  h      = (float*)alloc((size_t)n * 128 * 4);
    float*  xw2    = (float*)alloc((size_t)n * 32 * 4);
    int2*   tmp    = (int2*)h;             // binned edges alias h (used before agg128)

    const int nb_scan = (n + 1023) / 1024;

    init_counts<<<256, 256, 0, stream>>>(counts, cursor, n);
    count_kernel<<<2048, 256, 0, stream>>>(dst, counts, e);
    dinv_kernel<<<(n + 255) / 256, 256, 0, stream>>>(counts, dinv, n);
    scan_partial<<<nb_scan, 256, 0, stream>>>(counts, offs, bsums, n);
    scan_bsums<<<1, 256, 0, stream>>>(bsums, nb_scan);
    scan_add<<<512, 256, 0, stream>>>(offs, bsums, n, e);
    bin_cursor_init<<<(nbins + 255) / 256, 256, 0, stream>>>(offs, bin_cursor, nbins, n);
    bin_scatter<<<2048, 256, 0, stream>>>(src, dst, bin_cursor, tmp, e);
    fill_from_binned<<<2048, 256, 0, stream>>>(tmp, offs, cursor, dinv, csr, e);
    packW1_kernel<<<64, 256, 0, stream>>>(W1, W1f);

    // layer 1: xw1b = bf16(x@W1) via MFMA ; h = relu(agg(xw1b) + b1)
    mfma1_kernel<<<(n + 63) / 64, 256, 0, stream>>>(x, W1f, xw1b, n);
    agg128_kernel<<<(n + 3) / 4, 256, 0, stream>>>(xw1b, offs, csr, dinv, b1, h, n, 1);

    // layer 2: xw2 = h@W2 ; out = agg(xw2) + b2
    matmul_kernel<64, 32><<<(n + 63) / 64, 128, 0, stream>>>(h, W2, xw2, n);
    agg32_kernel<<<(n + 3) / 4, 256, 0, stream>>>(xw2, offs, csr, dinv, b2, out, n);
}

// Round 6
// 321.644 us; speedup vs baseline: 1.1655x; 1.1655x over previous
//
#include <hip/hip_runtime.h>

// ---------------------------------------------------------------------------
// 2-layer GCN: z = A_hat (relu(A_hat (X W1) + b1)) W2 + b2
// CSR-by-dst built once; transform-then-aggregate for both layers.
// R6: fill_kernel partitioned by dst-range (8 ranges, range = bid&7 so each
// XCD's L2 owns one range's CSR lines -> scattered 8B writes merge to full
// lines). Edge list read 8x (LLC-served). R5's binning reverted (cross-XCD
// line ping-pong made it useless).
// ---------------------------------------------------------------------------

#define KDIM 128
#define NRANGE 8

typedef unsigned int uint;
typedef unsigned short ushort;
typedef __attribute__((ext_vector_type(8))) short bf16x8;
typedef __attribute__((ext_vector_type(4))) float f32x4;

__device__ inline ushort f2bf(float f) {              // RNE f32 -> bf16
    uint u = __float_as_uint(f);
    return (ushort)((u + 0x7fffu + ((u >> 16) & 1u)) >> 16);
}

__global__ void init_counts(int* counts, int* cursor, int n) {
    int i = blockIdx.x * blockDim.x + threadIdx.x;
    int stride = gridDim.x * blockDim.x;
    for (; i < n; i += stride) { counts[i] = 0; cursor[i] = 0; }
}

__global__ void count_kernel(const int* __restrict__ dst, int* __restrict__ counts, int e) {
    int i = blockIdx.x * blockDim.x + threadIdx.x;
    int stride = gridDim.x * blockDim.x;
    for (; i < e; i += stride) atomicAdd(&counts[dst[i]], 1);
}

__global__ void dinv_kernel(const int* __restrict__ counts, float* __restrict__ dinv, int n) {
    int i = blockIdx.x * blockDim.x + threadIdx.x;
    int stride = gridDim.x * blockDim.x;
    for (; i < n; i += stride) dinv[i] = rsqrtf((float)(counts[i] + 1));
}

// --- 3-kernel exclusive scan over counts -> offsets -------------------------
__global__ void scan_partial(const int* __restrict__ counts, int* __restrict__ local,
                             int* __restrict__ bsums, int n) {
    __shared__ int ld[1024];
    __shared__ int ts[256];
    const int t = threadIdx.x;
    const int base = blockIdx.x * 1024;
    for (int j = t; j < 1024; j += 256) ld[j] = (base + j < n) ? counts[base + j] : 0;
    __syncthreads();
    int a0 = ld[4*t], a1 = ld[4*t+1], a2 = ld[4*t+2], a3 = ld[4*t+3];
    int sum = a0 + a1 + a2 + a3;
    ts[t] = sum;
    for (int off = 1; off < 256; off <<= 1) {
        __syncthreads();
        int v = (t >= off) ? ts[t - off] : 0;
        __syncthreads();
        ts[t] += v;
    }
    __syncthreads();
    int excl = ts[t] - sum;
    if (base + 4*t + 0 < n) local[base + 4*t + 0] = excl;
    if (base + 4*t + 1 < n) local[base + 4*t + 1] = excl + a0;
    if (base + 4*t + 2 < n) local[base + 4*t + 2] = excl + a0 + a1;
    if (base + 4*t + 3 < n) local[base + 4*t + 3] = excl + a0 + a1 + a2;
    if (t == 255) bsums[blockIdx.x] = ts[255];
}

__global__ void scan_bsums(int* __restrict__ bsums, int nb) {
    __shared__ int ts[256];
    const int t = threadIdx.x;
    int v = (t < nb) ? bsums[t] : 0;
    ts[t] = v;
    for (int off = 1; off < 256; off <<= 1) {
        __syncthreads();
        int u = (t >= off) ? ts[t - off] : 0;
        __syncthreads();
        ts[t] += u;
    }
    __syncthreads();
    if (t < nb) bsums[t] = ts[t] - v;
}

__global__ void scan_add(int* __restrict__ offs, const int* __restrict__ bsums, int n, int e_total) {
    int i = blockIdx.x * blockDim.x + threadIdx.x;
    int stride = gridDim.x * blockDim.x;
    for (; i < n; i += stride) offs[i] += bsums[i >> 10];
    if (blockIdx.x == 0 && threadIdx.x == 0) offs[n] = e_total;
}

// --- CSR fill, dst-range partitioned ----------------------------------------
// range r = bid & 7 handles dst in [r*rsize, (r+1)*rsize). With round-robin
// blockIdx->XCD placement, each XCD's L2 owns one range's CSR lines, so the
// random 8B record writes merge into full-line writebacks. Correct for ANY
// placement; placement only affects merge efficiency.
__global__ void fill_kernel(const int* __restrict__ src, const int* __restrict__ dst,
                            const int* __restrict__ offs, int* __restrict__ cursor,
                            const float* __restrict__ dinv,
                            int2* __restrict__ csr, int e, int n) {
    const int r = blockIdx.x & (NRANGE - 1);
    const int g = blockIdx.x >> 3;                     // index within range-group
    const int rsize = (n + NRANGE - 1) / NRANGE;
    const int lo = r * rsize;
    const int hi = min(lo + rsize, n);
    const int stride = (gridDim.x >> 3) * blockDim.x;
    int i = g * blockDim.x + threadIdx.x;
    for (; i < e; i += stride) {
        int d = dst[i];
        if (d < lo || d >= hi) continue;
        int s = src[i];
        int pos = offs[d] + atomicAdd(&cursor[d], 1);
        csr[pos] = make_int2(s, __float_as_int(dinv[s] * dinv[d]));
    }
}

// --- pack W1 (f32 [128][128]) into bf16 B-fragment order --------------------
__global__ void packW1_kernel(const float* __restrict__ W1, ushort* __restrict__ W1f) {
    int idx = blockIdx.x * blockDim.x + threadIdx.x;   // 16384 total
    int k = idx >> 7, col = idx & 127;
    int c = col >> 4, lcol = col & 15;
    int t = k >> 5, u = (k >> 3) & 3, j = k & 7;
    int lane = u * 16 + lcol;
    W1f[(size_t)(((c * 4 + t) * 64 + lane) * 8 + j)] = f2bf(W1[idx]);
}

// --- matmul1 via MFMA: xw1b[n x 128] (bf16) = x @ W1 ------------------------
__global__ __launch_bounds__(256)
void mfma1_kernel(const float* __restrict__ x, const ushort* __restrict__ W1f,
                  ushort* __restrict__ outb, int n) {
    __shared__ ushort bsm[16384];                      // 32 KB, frag order
    const int tid = threadIdx.x;
    #pragma unroll
    for (int j = 0; j < 8; ++j)
        ((uint4*)bsm)[tid + j * 256] = ((const uint4*)W1f)[tid + j * 256];

    const int w = tid >> 6;
    const int lane = tid & 63;
    const int r = lane & 15;
    const int u = lane >> 4;
    const int row0 = blockIdx.x * 64 + w * 16;
    int arow = row0 + r; if (arow >= n) arow = n - 1;

    bf16x8 afr[4];
    #pragma unroll
    for (int t = 0; t < 4; ++t) {
        const float* px = &x[(size_t)arow * 128 + t * 32 + u * 8];
        f32x4 v0 = *(const f32x4*)px;
        f32x4 v1 = *(const f32x4*)(px + 4);
        bf16x8 a;
        a[0] = (short)f2bf(v0[0]); a[1] = (short)f2bf(v0[1]);
        a[2] = (short)f2bf(v0[2]); a[3] = (short)f2bf(v0[3]);
        a[4] = (short)f2bf(v1[0]); a[5] = (short)f2bf(v1[1]);
        a[6] = (short)f2bf(v1[2]); a[7] = (short)f2bf(v1[3]);
        afr[t] = a;
    }
    __syncthreads();

    f32x4 acc[8];
    #pragma unroll
    for (int c = 0; c < 8; ++c) acc[c] = (f32x4){0.f, 0.f, 0.f, 0.f};

    #pragma unroll
    for (int c = 0; c < 8; ++c) {
        #pragma unroll
        for (int t = 0; t < 4; ++t) {
            bf16x8 b = *(const bf16x8*)&bsm[(size_t)(((c * 4 + t) * 64 + lane) * 8)];
            acc[c] = __builtin_amdgcn_mfma_f32_16x16x32_bf16(afr[t], b, acc[c], 0, 0, 0);
        }
    }

    #pragma unroll
    for (int c = 0; c < 8; ++c) {
        #pragma unroll
        for (int rr = 0; rr < 4; ++rr) {
            int row = row0 + u * 4 + rr;
            if (row < n) outb[(size_t)row * 128 + c * 16 + r] = f2bf(acc[c][rr]);
        }
    }
}

// --- generic small matmul (layer 2): out[n x DOUT] = x[n x 128] @ W ---------
template<int ROWS, int DOUT>
__global__ __launch_bounds__((ROWS/4)*(DOUT/4))
void matmul_kernel(const float* __restrict__ x, const float* __restrict__ W,
                   float* __restrict__ out, int n) {
    constexpr int K = KDIM;
    constexpr int TPB = (ROWS/4) * (DOUT/4);
    __shared__ float xs[ROWS][K];
    __shared__ float ws[K][DOUT];
    const int tid = threadIdx.x;
    const int row0 = blockIdx.x * ROWS;

    for (int idx = tid; idx < K*DOUT/4; idx += TPB)
        ((float4*)ws)[idx] = ((const float4*)W)[idx];
    for (int idx = tid; idx < ROWS*K/4; idx += TPB) {
        int r = idx / (K/4);
        int row = row0 + r;
        float4 v = (row < n) ? ((const float4*)x)[(size_t)row*(K/4) + (idx % (K/4))]
                             : make_float4(0.f, 0.f, 0.f, 0.f);
        ((float4*)xs)[idx] = v;
    }
    __syncthreads();

    const int tc = tid % (DOUT/4);
    const int tr = tid / (DOUT/4);
    float acc[4][4] = {};
    #pragma unroll 4
    for (int k = 0; k < K; k += 4) {
        float xa[4][4], wb[4][4];
        #pragma unroll
        for (int r = 0; r < 4; ++r) {
            float4 v = *(const float4*)&xs[tr*4 + r][k];
            xa[r][0] = v.x; xa[r][1] = v.y; xa[r][2] = v.z; xa[r][3] = v.w;
        }
        #pragma unroll
        for (int kk = 0; kk < 4; ++kk) {
            float4 v = *(const float4*)&ws[k + kk][tc*4];
            wb[kk][0] = v.x; wb[kk][1] = v.y; wb[kk][2] = v.z; wb[kk][3] = v.w;
        }
        #pragma unroll
        for (int r = 0; r < 4; ++r)
            #pragma unroll
            for (int kk = 0; kk < 4; ++kk)
                #pragma unroll
                for (int c = 0; c < 4; ++c)
                    acc[r][c] += xa[r][kk] * wb[kk][c];
    }
    #pragma unroll
    for (int r = 0; r < 4; ++r) {
        int row = row0 + tr*4 + r;
        if (row < n) {
            float4 v = make_float4(acc[r][0], acc[r][1], acc[r][2], acc[r][3]);
            *(float4*)&out[(size_t)row*DOUT + tc*4] = v;
        }
    }
}

// --- aggregation, D=128 over bf16 rows: one wave per node -------------------
__device__ inline void bf2_fma(uint u, float nr, float& a0, float& a1) {
    a0 += __uint_as_float(u << 16) * nr;
    a1 += __uint_as_float(u & 0xffff0000u) * nr;
}

__global__ __launch_bounds__(256)
void agg128_kernel(const ushort* __restrict__ xwb, const int* __restrict__ offs,
                   const int2* __restrict__ csr, const float* __restrict__ dinv,
                   const float* __restrict__ bias, float* __restrict__ out,
                   int n, int do_relu) {
    const int w = threadIdx.x >> 6;
    const int i = blockIdx.x * 4 + w;
    if (i >= n) return;
    const int lane = threadIdx.x & 63;
    const int g = lane >> 4;
    const int q = lane & 15;

    float acc[8] = {};
    const int e0 = offs[i], e1 = offs[i + 1];
    int e = e0 + g;
    for (; e + 4 < e1; e += 8) {
        int2 p0 = csr[e];
        int2 p1 = csr[e + 4];
        uint4 u0 = *(const uint4*)&xwb[(size_t)p0.x * 128 + q * 8];
        uint4 u1 = *(const uint4*)&xwb[(size_t)p1.x * 128 + q * 8];
        float n0 = __int_as_float(p0.y);
        float n1 = __int_as_float(p1.y);
        bf2_fma(u0.x, n0, acc[0], acc[1]);
        bf2_fma(u0.y, n0, acc[2], acc[3]);
        bf2_fma(u0.z, n0, acc[4], acc[5]);
        bf2_fma(u0.w, n0, acc[6], acc[7]);
        bf2_fma(u1.x, n1, acc[0], acc[1]);
        bf2_fma(u1.y, n1, acc[2], acc[3]);
        bf2_fma(u1.z, n1, acc[4], acc[5]);
        bf2_fma(u1.w, n1, acc[6], acc[7]);
    }
    if (e < e1) {
        int2 p = csr[e];
        uint4 u = *(const uint4*)&xwb[(size_t)p.x * 128 + q * 8];
        float nr = __int_as_float(p.y);
        bf2_fma(u.x, nr, acc[0], acc[1]);
        bf2_fma(u.y, nr, acc[2], acc[3]);
        bf2_fma(u.z, nr, acc[4], acc[5]);
        bf2_fma(u.w, nr, acc[6], acc[7]);
    }
    #pragma unroll
    for (int j = 0; j < 8; ++j) {
        acc[j] += __shfl_xor(acc[j], 16, 64);
        acc[j] += __shfl_xor(acc[j], 32, 64);
    }

    if (g == 0) {
        const float di = dinv[i];
        const float s = di * di;
        uint4 su = *(const uint4*)&xwb[(size_t)i * 128 + q * 8];
        bf2_fma(su.x, s, acc[0], acc[1]);
        bf2_fma(su.y, s, acc[2], acc[3]);
        bf2_fma(su.z, s, acc[4], acc[5]);
        bf2_fma(su.w, s, acc[6], acc[7]);
        const float4 b0 = *(const float4*)&bias[q * 8];
        const float4 b1 = *(const float4*)&bias[q * 8 + 4];
        float4 r0, r1;
        r0.x = acc[0] + b0.x; r0.y = acc[1] + b0.y; r0.z = acc[2] + b0.z; r0.w = acc[3] + b0.w;
        r1.x = acc[4] + b1.x; r1.y = acc[5] + b1.y; r1.z = acc[6] + b1.z; r1.w = acc[7] + b1.w;
        if (do_relu) {
            r0.x = fmaxf(r0.x, 0.f); r0.y = fmaxf(r0.y, 0.f);
            r0.z = fmaxf(r0.z, 0.f); r0.w = fmaxf(r0.w, 0.f);
            r1.x = fmaxf(r1.x, 0.f); r1.y = fmaxf(r1.y, 0.f);
            r1.z = fmaxf(r1.z, 0.f); r1.w = fmaxf(r1.w, 0.f);
        }
        *(float4*)&out[(size_t)i * 128 + q * 8] = r0;
        *(float4*)&out[(size_t)i * 128 + q * 8 + 4] = r1;
    }
}

// --- aggregation, D=32 (f32): one wave per node, 8 edges in parallel --------
__global__ __launch_bounds__(256)
void agg32_kernel(const float* __restrict__ xw, const int* __restrict__ offs,
                  const int2* __restrict__ csr, const float* __restrict__ dinv,
                  const float* __restrict__ bias, float* __restrict__ out, int n) {
    const int w = threadIdx.x >> 6;
    const int i = blockIdx.x * 4 + w;
    if (i >= n) return;
    const int lane = threadIdx.x & 63;
    const int g = lane >> 3;
    const int q = lane & 7;

    float4 acc = make_float4(0.f, 0.f, 0.f, 0.f);
    const int e0 = offs[i], e1 = offs[i + 1];
    int e = e0 + g;
    for (; e + 8 < e1; e += 16) {
        int2 p0 = csr[e];
        int2 p1 = csr[e + 8];
        const float4 v0 = *(const float4*)&xw[(size_t)p0.x * 32 + q * 4];
        const float4 v1 = *(const float4*)&xw[(size_t)p1.x * 32 + q * 4];
        const float n0 = __int_as_float(p0.y);
        const float n1 = __int_as_float(p1.y);
        acc.x += v0.x * n0; acc.y += v0.y * n0; acc.z += v0.z * n0; acc.w += v0.w * n0;
        acc.x += v1.x * n1; acc.y += v1.y * n1; acc.z += v1.z * n1; acc.w += v1.w * n1;
    }
    if (e < e1) {
        int2 p = csr[e];
        const float4 v = *(const float4*)&xw[(size_t)p.x * 32 + q * 4];
        const float nr = __int_as_float(p.y);
        acc.x += v.x * nr; acc.y += v.y * nr; acc.z += v.z * nr; acc.w += v.w * nr;
    }
    #pragma unroll
    for (int m = 8; m <= 32; m <<= 1) {
        acc.x += __shfl_xor(acc.x, m, 64);
        acc.y += __shfl_xor(acc.y, m, 64);
        acc.z += __shfl_xor(acc.z, m, 64);
        acc.w += __shfl_xor(acc.w, m, 64);
    }

    if (g == 0) {
        const float di = dinv[i];
        const float s = di * di;
        const float4 sv = *(const float4*)&xw[(size_t)i * 32 + q * 4];
        const float4 b  = *(const float4*)&bias[q * 4];
        float4 r;
        r.x = acc.x + sv.x * s + b.x;
        r.y = acc.y + sv.y * s + b.y;
        r.z = acc.z + sv.z * s + b.z;
        r.w = acc.w + sv.w * s + b.w;
        *(float4*)&out[(size_t)i * 32 + q * 4] = r;
    }
}

extern "C" void kernel_launch(void* const* d_in, const int* in_sizes, int n_in,
                              void* d_out, int out_size, void* d_ws, size_t ws_size,
                              hipStream_t stream) {
    const int n = in_sizes[0] / KDIM;      // 100000
    const int e = in_sizes[1] / 2;         // 1600000

    const float* x  = (const float*)d_in[0];
    const int*   ei = (const int*)d_in[1];
    const int*   src = ei;
    const int*   dst = ei + e;
    const float* W1 = (const float*)d_in[2];
    const float* b1 = (const float*)d_in[3];
    const float* W2 = (const float*)d_in[4];
    const float* b2 = (const float*)d_in[5];
    float* out = (float*)d_out;

    // workspace carve (256B aligned)
    char* p = (char*)d_ws;
    auto alloc = [&](size_t bytes) { char* q = p; p += (bytes + 255) & ~(size_t)255; return q; };
    float*  dinv   = (float*)alloc((size_t)n * 4);
    int*    counts = (int*)  alloc((size_t)n * 4);
    int*    cursor = (int*)  alloc((size_t)n * 4);
    int*    offs   = (int*)  alloc((size_t)(n + 1) * 4);
    int*    bsums  = (int*)  alloc(1024 * 4);
    int2*   csr    = (int2*) alloc((size_t)e * 8);
    ushort* W1f    = (ushort*)alloc((size_t)128 * 128 * 2);
    ushort* xw1b   = (ushort*)alloc((size_t)n * 128 * 2);
    float*  h      = (float*)alloc((size_t)n * 128 * 4);
    float*  xw2    = (float*)alloc((size_t)n * 32 * 4);

    const int nb_scan = (n + 1023) / 1024;

    init_counts<<<256, 256, 0, stream>>>(counts, cursor, n);
    count_kernel<<<1024, 256, 0, stream>>>(dst, counts, e);
    dinv_kernel<<<(n + 255) / 256, 256, 0, stream>>>(counts, dinv, n);
    scan_partial<<<nb_scan, 256, 0, stream>>>(counts, offs, bsums, n);
    scan_bsums<<<1, 256, 0, stream>>>(bsums, nb_scan);
    scan_add<<<512, 256, 0, stream>>>(offs, bsums, n, e);
    fill_kernel<<<2048, 256, 0, stream>>>(src, dst, offs, cursor, dinv, csr, e, n);
    packW1_kernel<<<64, 256, 0, stream>>>(W1, W1f);

    // layer 1: xw1b = bf16(x@W1) via MFMA ; h = relu(agg(xw1b) + b1)
    mfma1_kernel<<<(n + 63) / 64, 256, 0, stream>>>(x, W1f, xw1b, n);
    agg128_kernel<<<(n + 3) / 4, 256, 0, stream>>>(xw1b, offs, csr, dinv, b1, h, n, 1);

    // layer 2: xw2 = h@W2 ; out = agg(xw2) + b2
    matmul_kernel<64, 32><<<(n + 63) / 64, 128, 0, stream>>>(h, W2, xw2, n);
    agg32_kernel<<<(n + 3) / 4, 256, 0, stream>>>(xw2, offs, csr, dinv, b2, out, n);
}

// Round 7
// 286.312 us; speedup vs baseline: 1.3093x; 1.1234x over previous
//
#include <hip/hip_runtime.h>

// ---------------------------------------------------------------------------
// 2-layer GCN: z = A_hat (relu(A_hat (X W1) + b1)) W2 + b2
// CSR-by-dst built once; transform-then-aggregate for both layers.
// R7: CSR build rebuilt as LDS-staged two-pass sort:
//   binA: LDS bins by dst>>9, contiguous coalesced flushes into exact bucket
//         regions (4B packed records) -- single-WG line ownership on writes.
//   sortB: one WG per 512-node window, LDS counting sort, coalesced CSR copy.
// CSR record = src only (4B); aggs compute norm = dinv[s]*dinv[d] inline.
// (R5 global-bin scatter and R6 dst-range scatter both failed: sub-line
//  scattered writes from multiple WGs never merge -> 1 line writeback/record.)
// ---------------------------------------------------------------------------

#define KDIM 128
#define PA_NB 196      // max node-windows: ceil(100352/512)
#define PA_CAP 64      // records per LDS bin (avg 32 at 256 WGs)
#define PB_CAP 10240   // LDS records per window sort (avg 8192)

typedef unsigned int uint;
typedef unsigned short ushort;
typedef __attribute__((ext_vector_type(8))) short bf16x8;
typedef __attribute__((ext_vector_type(4))) float f32x4;

__device__ inline ushort f2bf(float f) {              // RNE f32 -> bf16
    uint u = __float_as_uint(f);
    return (ushort)((u + 0x7fffu + ((u >> 16) & 1u)) >> 16);
}

__global__ void init_counts(int* counts, int n) {
    int i = blockIdx.x * blockDim.x + threadIdx.x;
    int stride = gridDim.x * blockDim.x;
    for (; i < n; i += stride) counts[i] = 0;
}

__global__ void count_kernel(const int* __restrict__ dst, int* __restrict__ counts, int e) {
    int i = blockIdx.x * blockDim.x + threadIdx.x;
    int stride = gridDim.x * blockDim.x;
    for (; i < e; i += stride) atomicAdd(&counts[dst[i]], 1);
}

__global__ void dinv_kernel(const int* __restrict__ counts, float* __restrict__ dinv, int n) {
    int i = blockIdx.x * blockDim.x + threadIdx.x;
    int stride = gridDim.x * blockDim.x;
    for (; i < n; i += stride) dinv[i] = rsqrtf((float)(counts[i] + 1));
}

// --- 3-kernel exclusive scan over counts -> offsets -------------------------
__global__ void scan_partial(const int* __restrict__ counts, int* __restrict__ local,
                             int* __restrict__ bsums, int n) {
    __shared__ int ld[1024];
    __shared__ int ts[256];
    const int t = threadIdx.x;
    const int base = blockIdx.x * 1024;
    for (int j = t; j < 1024; j += 256) ld[j] = (base + j < n) ? counts[base + j] : 0;
    __syncthreads();
    int a0 = ld[4*t], a1 = ld[4*t+1], a2 = ld[4*t+2], a3 = ld[4*t+3];
    int sum = a0 + a1 + a2 + a3;
    ts[t] = sum;
    for (int off = 1; off < 256; off <<= 1) {
        __syncthreads();
        int v = (t >= off) ? ts[t - off] : 0;
        __syncthreads();
        ts[t] += v;
    }
    __syncthreads();
    int excl = ts[t] - sum;
    if (base + 4*t + 0 < n) local[base + 4*t + 0] = excl;
    if (base + 4*t + 1 < n) local[base + 4*t + 1] = excl + a0;
    if (base + 4*t + 2 < n) local[base + 4*t + 2] = excl + a0 + a1;
    if (base + 4*t + 3 < n) local[base + 4*t + 3] = excl + a0 + a1 + a2;
    if (t == 255) bsums[blockIdx.x] = ts[255];
}

__global__ void scan_bsums(int* __restrict__ bsums, int nb) {
    __shared__ int ts[256];
    const int t = threadIdx.x;
    int v = (t < nb) ? bsums[t] : 0;
    ts[t] = v;
    for (int off = 1; off < 256; off <<= 1) {
        __syncthreads();
        int u = (t >= off) ? ts[t - off] : 0;
        __syncthreads();
        ts[t] += u;
    }
    __syncthreads();
    if (t < nb) bsums[t] = ts[t] - v;
}

__global__ void scan_add(int* __restrict__ offs, const int* __restrict__ bsums, int n, int e_total) {
    int i = blockIdx.x * blockDim.x + threadIdx.x;
    int stride = gridDim.x * blockDim.x;
    for (; i < n; i += stride) offs[i] += bsums[i >> 10];
    if (blockIdx.x == 0 && threadIdx.x == 0) offs[n] = e_total;
}

__global__ void gcur_init(const int* __restrict__ offs, int* __restrict__ gcur,
                          int nb, int n) {
    int b = blockIdx.x * blockDim.x + threadIdx.x;
    if (b < nb) gcur[b] = offs[min(b << 9, n)];
}

// --- pass A: LDS-staged binning into exact per-window bucket regions --------
// Each WG owns a contiguous edge chunk; bins records (dlow<<17|src, 4B) into
// LDS by window b = dst>>9; drains each bin as ONE contiguous coalesced chunk
// (global cursor reserve). All tmp lines written by few WGs in large chunks.
__global__ __launch_bounds__(256)
void binA_kernel(const int* __restrict__ src, const int* __restrict__ dst,
                 int* __restrict__ gcur, int* __restrict__ tmp, int e, int nb) {
    __shared__ int lbuf[PA_NB * PA_CAP];   // 50176 B
    __shared__ int cnt[PA_NB];
    __shared__ int gbase[PA_NB];
    const int tid = threadIdx.x;
    for (int b = tid; b < nb; b += 256) cnt[b] = 0;
    __syncthreads();

    const int per = (e + gridDim.x - 1) / gridDim.x;
    const int i0 = blockIdx.x * per;
    const int i1 = min(i0 + per, e);
    for (int i = i0 + tid; i < i1; i += 256) {
        int d = dst[i];
        int s = src[i];
        int b = d >> 9;
        int rec = ((d & 511) << 17) | s;
        int p = atomicAdd(&cnt[b], 1);
        if (p < PA_CAP) lbuf[b * PA_CAP + p] = rec;
        else tmp[atomicAdd(&gcur[b], 1)] = rec;   // rare overflow, still correct
    }
    __syncthreads();
    if (tid < nb) {
        int lvl = min(cnt[tid], PA_CAP);
        cnt[tid] = lvl;
        gbase[tid] = lvl ? atomicAdd(&gcur[tid], lvl) : 0;
    }
    __syncthreads();
    for (int bb = 0; bb < nb; bb += 4) {       // 4 bins per iter (one per wave)
        int b = bb + (tid >> 6);
        if (b < nb) {
            int lvl = cnt[b];
            int l = tid & 63;
            if (l < lvl) tmp[gbase[b] + l] = lbuf[b * PA_CAP + l];
        }
    }
}

// --- pass B: per-window LDS counting sort -> final CSR (coalesced write) ----
__global__ __launch_bounds__(256)
void sortB_kernel(const int* __restrict__ tmp, const int* __restrict__ offs,
                  int* __restrict__ csr, int n) {
    __shared__ int lcsr[PB_CAP];           // 40 KB
    __shared__ int cur[512];
    const int w = blockIdx.x;
    const int tid = threadIdx.x;
    const int node0 = w << 9;
    const int nloc = min(512, n - node0);
    const int base = offs[node0];
    const int end  = offs[min(node0 + 512, n)];
    for (int j = tid; j < nloc; j += 256) cur[j] = offs[node0 + j] - base;
    __syncthreads();
    for (int i = base + tid; i < end; i += 256) {
        int rec = tmp[i];
        int dl = (rec >> 17) & 511;
        int s = rec & 0x1FFFF;
        int p = atomicAdd(&cur[dl], 1);
        if (p < PB_CAP) lcsr[p] = s;
        else csr[base + p] = s;            // pathological overflow fallback
    }
    __syncthreads();
    const int lim = min(end - base, PB_CAP);
    for (int i = tid; i < lim; i += 256) csr[base + i] = lcsr[i];
}

// --- pack W1 (f32 [128][128]) into bf16 B-fragment order --------------------
__global__ void packW1_kernel(const float* __restrict__ W1, ushort* __restrict__ W1f) {
    int idx = blockIdx.x * blockDim.x + threadIdx.x;   // 16384 total
    int k = idx >> 7, col = idx & 127;
    int c = col >> 4, lcol = col & 15;
    int t = k >> 5, u = (k >> 3) & 3, j = k & 7;
    int lane = u * 16 + lcol;
    W1f[(size_t)(((c * 4 + t) * 64 + lane) * 8 + j)] = f2bf(W1[idx]);
}

// --- matmul1 via MFMA: xw1b[n x 128] (bf16) = x @ W1 ------------------------
__global__ __launch_bounds__(256)
void mfma1_kernel(const float* __restrict__ x, const ushort* __restrict__ W1f,
                  ushort* __restrict__ outb, int n) {
    __shared__ ushort bsm[16384];                      // 32 KB, frag order
    const int tid = threadIdx.x;
    #pragma unroll
    for (int j = 0; j < 8; ++j)
        ((uint4*)bsm)[tid + j * 256] = ((const uint4*)W1f)[tid + j * 256];

    const int w = tid >> 6;
    const int lane = tid & 63;
    const int r = lane & 15;
    const int u = lane >> 4;
    const int row0 = blockIdx.x * 64 + w * 16;
    int arow = row0 + r; if (arow >= n) arow = n - 1;

    bf16x8 afr[4];
    #pragma unroll
    for (int t = 0; t < 4; ++t) {
        const float* px = &x[(size_t)arow * 128 + t * 32 + u * 8];
        f32x4 v0 = *(const f32x4*)px;
        f32x4 v1 = *(const f32x4*)(px + 4);
        bf16x8 a;
        a[0] = (short)f2bf(v0[0]); a[1] = (short)f2bf(v0[1]);
        a[2] = (short)f2bf(v0[2]); a[3] = (short)f2bf(v0[3]);
        a[4] = (short)f2bf(v1[0]); a[5] = (short)f2bf(v1[1]);
        a[6] = (short)f2bf(v1[2]); a[7] = (short)f2bf(v1[3]);
        afr[t] = a;
    }
    __syncthreads();

    f32x4 acc[8];
    #pragma unroll
    for (int c = 0; c < 8; ++c) acc[c] = (f32x4){0.f, 0.f, 0.f, 0.f};

    #pragma unroll
    for (int c = 0; c < 8; ++c) {
        #pragma unroll
        for (int t = 0; t < 4; ++t) {
            bf16x8 b = *(const bf16x8*)&bsm[(size_t)(((c * 4 + t) * 64 + lane) * 8)];
            acc[c] = __builtin_amdgcn_mfma_f32_16x16x32_bf16(afr[t], b, acc[c], 0, 0, 0);
        }
    }

    #pragma unroll
    for (int c = 0; c < 8; ++c) {
        #pragma unroll
        for (int rr = 0; rr < 4; ++rr) {
            int row = row0 + u * 4 + rr;
            if (row < n) outb[(size_t)row * 128 + c * 16 + r] = f2bf(acc[c][rr]);
        }
    }
}

// --- generic small matmul (layer 2): out[n x DOUT] = x[n x 128] @ W ---------
template<int ROWS, int DOUT>
__global__ __launch_bounds__((ROWS/4)*(DOUT/4))
void matmul_kernel(const float* __restrict__ x, const float* __restrict__ W,
                   float* __restrict__ out, int n) {
    constexpr int K = KDIM;
    constexpr int TPB = (ROWS/4) * (DOUT/4);
    __shared__ float xs[ROWS][K];
    __shared__ float ws[K][DOUT];
    const int tid = threadIdx.x;
    const int row0 = blockIdx.x * ROWS;

    for (int idx = tid; idx < K*DOUT/4; idx += TPB)
        ((float4*)ws)[idx] = ((const float4*)W)[idx];
    for (int idx = tid; idx < ROWS*K/4; idx += TPB) {
        int r = idx / (K/4);
        int row = row0 + r;
        float4 v = (row < n) ? ((const float4*)x)[(size_t)row*(K/4) + (idx % (K/4))]
                             : make_float4(0.f, 0.f, 0.f, 0.f);
        ((float4*)xs)[idx] = v;
    }
    __syncthreads();

    const int tc = tid % (DOUT/4);
    const int tr = tid / (DOUT/4);
    float acc[4][4] = {};
    #pragma unroll 4
    for (int k = 0; k < K; k += 4) {
        float xa[4][4], wb[4][4];
        #pragma unroll
        for (int r = 0; r < 4; ++r) {
            float4 v = *(const float4*)&xs[tr*4 + r][k];
            xa[r][0] = v.x; xa[r][1] = v.y; xa[r][2] = v.z; xa[r][3] = v.w;
        }
        #pragma unroll
        for (int kk = 0; kk < 4; ++kk) {
            float4 v = *(const float4*)&ws[k + kk][tc*4];
            wb[kk][0] = v.x; wb[kk][1] = v.y; wb[kk][2] = v.z; wb[kk][3] = v.w;
        }
        #pragma unroll
        for (int r = 0; r < 4; ++r)
            #pragma unroll
            for (int kk = 0; kk < 4; ++kk)
                #pragma unroll
                for (int c = 0; c < 4; ++c)
                    acc[r][c] += xa[r][kk] * wb[kk][c];
    }
    #pragma unroll
    for (int r = 0; r < 4; ++r) {
        int row = row0 + tr*4 + r;
        if (row < n) {
            float4 v = make_float4(acc[r][0], acc[r][1], acc[r][2], acc[r][3]);
            *(float4*)&out[(size_t)row*DOUT + tc*4] = v;
        }
    }
}

// --- aggregation, D=128 over bf16 rows: one wave per node -------------------
__device__ inline void bf2_fma(uint u, float nr, float& a0, float& a1) {
    a0 += __uint_as_float(u << 16) * nr;
    a1 += __uint_as_float(u & 0xffff0000u) * nr;
}

__global__ __launch_bounds__(256)
void agg128_kernel(const ushort* __restrict__ xwb, const int* __restrict__ offs,
                   const int* __restrict__ csr, const float* __restrict__ dinv,
                   const float* __restrict__ bias, float* __restrict__ out,
                   int n, int do_relu) {
    const int w = threadIdx.x >> 6;
    const int i = blockIdx.x * 4 + w;
    if (i >= n) return;
    const int lane = threadIdx.x & 63;
    const int g = lane >> 4;
    const int q = lane & 15;
    const float di = dinv[i];

    float acc[8] = {};
    const int e0 = offs[i], e1 = offs[i + 1];
    int e = e0 + g;
    for (; e + 4 < e1; e += 8) {
        int s0 = csr[e];
        int s1 = csr[e + 4];
        uint4 u0 = *(const uint4*)&xwb[(size_t)s0 * 128 + q * 8];
        uint4 u1 = *(const uint4*)&xwb[(size_t)s1 * 128 + q * 8];
        float n0 = dinv[s0] * di;
        float n1 = dinv[s1] * di;
        bf2_fma(u0.x, n0, acc[0], acc[1]);
        bf2_fma(u0.y, n0, acc[2], acc[3]);
        bf2_fma(u0.z, n0, acc[4], acc[5]);
        bf2_fma(u0.w, n0, acc[6], acc[7]);
        bf2_fma(u1.x, n1, acc[0], acc[1]);
        bf2_fma(u1.y, n1, acc[2], acc[3]);
        bf2_fma(u1.z, n1, acc[4], acc[5]);
        bf2_fma(u1.w, n1, acc[6], acc[7]);
    }
    if (e < e1) {
        int s0 = csr[e];
        uint4 u = *(const uint4*)&xwb[(size_t)s0 * 128 + q * 8];
        float nr = dinv[s0] * di;
        bf2_fma(u.x, nr, acc[0], acc[1]);
        bf2_fma(u.y, nr, acc[2], acc[3]);
        bf2_fma(u.z, nr, acc[4], acc[5]);
        bf2_fma(u.w, nr, acc[6], acc[7]);
    }
    #pragma unroll
    for (int j = 0; j < 8; ++j) {
        acc[j] += __shfl_xor(acc[j], 16, 64);
        acc[j] += __shfl_xor(acc[j], 32, 64);
    }

    if (g == 0) {
        const float s = di * di;
        uint4 su = *(const uint4*)&xwb[(size_t)i * 128 + q * 8];
        bf2_fma(su.x, s, acc[0], acc[1]);
        bf2_fma(su.y, s, acc[2], acc[3]);
        bf2_fma(su.z, s, acc[4], acc[5]);
        bf2_fma(su.w, s, acc[6], acc[7]);
        const float4 b0 = *(const float4*)&bias[q * 8];
        const float4 b1 = *(const float4*)&bias[q * 8 + 4];
        float4 r0, r1;
        r0.x = acc[0] + b0.x; r0.y = acc[1] + b0.y; r0.z = acc[2] + b0.z; r0.w = acc[3] + b0.w;
        r1.x = acc[4] + b1.x; r1.y = acc[5] + b1.y; r1.z = acc[6] + b1.z; r1.w = acc[7] + b1.w;
        if (do_relu) {
            r0.x = fmaxf(r0.x, 0.f); r0.y = fmaxf(r0.y, 0.f);
            r0.z = fmaxf(r0.z, 0.f); r0.w = fmaxf(r0.w, 0.f);
            r1.x = fmaxf(r1.x, 0.f); r1.y = fmaxf(r1.y, 0.f);
            r1.z = fmaxf(r1.z, 0.f); r1.w = fmaxf(r1.w, 0.f);
        }
        *(float4*)&out[(size_t)i * 128 + q * 8] = r0;
        *(float4*)&out[(size_t)i * 128 + q * 8 + 4] = r1;
    }
}

// --- aggregation, D=32 (f32): one wave per node, 8 edges in parallel --------
__global__ __launch_bounds__(256)
void agg32_kernel(const float* __restrict__ xw, const int* __restrict__ offs,
                  const int* __restrict__ csr, const float* __restrict__ dinv,
                  const float* __restrict__ bias, float* __restrict__ out, int n) {
    const int w = threadIdx.x >> 6;
    const int i = blockIdx.x * 4 + w;
    if (i >= n) return;
    const int lane = threadIdx.x & 63;
    const int g = lane >> 3;
    const int q = lane & 7;
    const float di = dinv[i];

    float4 acc = make_float4(0.f, 0.f, 0.f, 0.f);
    const int e0 = offs[i], e1 = offs[i + 1];
    int e = e0 + g;
    for (; e + 8 < e1; e += 16) {
        int s0 = csr[e];
        int s1 = csr[e + 8];
        const float4 v0 = *(const float4*)&xw[(size_t)s0 * 32 + q * 4];
        const float4 v1 = *(const float4*)&xw[(size_t)s1 * 32 + q * 4];
        const float n0 = dinv[s0] * di;
        const float n1 = dinv[s1] * di;
        acc.x += v0.x * n0; acc.y += v0.y * n0; acc.z += v0.z * n0; acc.w += v0.w * n0;
        acc.x += v1.x * n1; acc.y += v1.y * n1; acc.z += v1.z * n1; acc.w += v1.w * n1;
    }
    if (e < e1) {
        int s0 = csr[e];
        const float4 v = *(const float4*)&xw[(size_t)s0 * 32 + q * 4];
        const float nr = dinv[s0] * di;
        acc.x += v.x * nr; acc.y += v.y * nr; acc.z += v.z * nr; acc.w += v.w * nr;
    }
    #pragma unroll
    for (int m = 8; m <= 32; m <<= 1) {
        acc.x += __shfl_xor(acc.x, m, 64);
        acc.y += __shfl_xor(acc.y, m, 64);
        acc.z += __shfl_xor(acc.z, m, 64);
        acc.w += __shfl_xor(acc.w, m, 64);
    }

    if (g == 0) {
        const float s = di * di;
        const float4 sv = *(const float4*)&xw[(size_t)i * 32 + q * 4];
        const float4 b  = *(const float4*)&bias[q * 4];
        float4 r;
        r.x = acc.x + sv.x * s + b.x;
        r.y = acc.y + sv.y * s + b.y;
        r.z = acc.z + sv.z * s + b.z;
        r.w = acc.w + sv.w * s + b.w;
        *(float4*)&out[(size_t)i * 32 + q * 4] = r;
    }
}

extern "C" void kernel_launch(void* const* d_in, const int* in_sizes, int n_in,
                              void* d_out, int out_size, void* d_ws, size_t ws_size,
                              hipStream_t stream) {
    const int n = in_sizes[0] / KDIM;      // 100000
    const int e = in_sizes[1] / 2;         // 1600000

    const float* x  = (const float*)d_in[0];
    const int*   ei = (const int*)d_in[1];
    const int*   src = ei;
    const int*   dst = ei + e;
    const float* W1 = (const float*)d_in[2];
    const float* b1 = (const float*)d_in[3];
    const float* W2 = (const float*)d_in[4];
    const float* b2 = (const float*)d_in[5];
    float* out = (float*)d_out;

    // workspace carve (256B aligned)
    char* p = (char*)d_ws;
    auto alloc = [&](size_t bytes) { char* q = p; p += (bytes + 255) & ~(size_t)255; return q; };
    const int nwin = (n + 511) >> 9;                   // 196 node-windows
    float*  dinv   = (float*)alloc((size_t)n * 4);
    int*    counts = (int*)  alloc((size_t)n * 4);
    int*    offs   = (int*)  alloc((size_t)(n + 1) * 4);
    int*    bsums  = (int*)  alloc(1024 * 4);
    int*    gcur   = (int*)  alloc((size_t)nwin * 4);
    int*    csr    = (int*)  alloc((size_t)e * 4);
    ushort* W1f    = (ushort*)alloc((size_t)128 * 128 * 2);
    ushort* xw1b   = (ushort*)alloc((size_t)n * 128 * 2);
    float*  h      = (float*)alloc((size_t)n * 128 * 4);
    float*  xw2    = (float*)alloc((size_t)n * 32 * 4);
    int*    tmp    = (int*)h;              // binned records alias h (free until agg128)

    const int nb_scan = (n + 1023) / 1024;

    init_counts<<<256, 256, 0, stream>>>(counts, n);
    count_kernel<<<2048, 256, 0, stream>>>(dst, counts, e);
    dinv_kernel<<<(n + 255) / 256, 256, 0, stream>>>(counts, dinv, n);
    scan_partial<<<nb_scan, 256, 0, stream>>>(counts, offs, bsums, n);
    scan_bsums<<<1, 256, 0, stream>>>(bsums, nb_scan);
    scan_add<<<512, 256, 0, stream>>>(offs, bsums, n, e);
    gcur_init<<<(nwin + 255) / 256, 256, 0, stream>>>(offs, gcur, nwin, n);
    binA_kernel<<<256, 256, 0, stream>>>(src, dst, gcur, tmp, e, nwin);
    sortB_kernel<<<nwin, 256, 0, stream>>>(tmp, offs, csr, n);
    packW1_kernel<<<64, 256, 0, stream>>>(W1, W1f);

    // layer 1: xw1b = bf16(x@W1) via MFMA ; h = relu(agg(xw1b) + b1)
    mfma1_kernel<<<(n + 63) / 64, 256, 0, stream>>>(x, W1f, xw1b, n);
    agg128_kernel<<<(n + 3) / 4, 256, 0, stream>>>(xw1b, offs, csr, dinv, b1, h, n, 1);

    // layer 2: xw2 = h@W2 ; out = agg(xw2) + b2
    matmul_kernel<64, 32><<<(n + 63) / 64, 128, 0, stream>>>(h, W2, xw2, n);
    agg32_kernel<<<(n + 3) / 4, 256, 0, stream>>>(xw2, offs, csr, dinv, b2, out, n);
}

// Round 8
// 254.763 us; speedup vs baseline: 1.4715x; 1.1238x over previous
//
#include <hip/hip_runtime.h>

// ---------------------------------------------------------------------------
// 2-layer GCN: z = A_hat (relu(A_hat (X W1) + b1)) W2 + b2
// CSR-by-dst (LDS-staged 2-pass sort). Transform-then-aggregate, with
// R8: dinv[src] folded into transformed rows (matmul epilogues), so aggs are
// plain sums + one dinv[d] scale at the end (no per-edge dinv loads/muls).
// h and xw2 stored bf16; matmul2 now MFMA. CSR record = src only (4B).
// ---------------------------------------------------------------------------

#define KDIM 128
#define PA_NB 196      // max node-windows: ceil(100352/512)
#define PA_CAP 64      // records per LDS bin
#define PB_CAP 10240   // LDS records per window sort

typedef unsigned int uint;
typedef unsigned short ushort;
typedef __attribute__((ext_vector_type(8))) short bf16x8;
typedef __attribute__((ext_vector_type(4))) float f32x4;

__device__ inline ushort f2bf(float f) {              // RNE f32 -> bf16
    uint u = __float_as_uint(f);
    return (ushort)((u + 0x7fffu + ((u >> 16) & 1u)) >> 16);
}

__global__ void init_counts(int* counts, int n) {
    int i = blockIdx.x * blockDim.x + threadIdx.x;
    int stride = gridDim.x * blockDim.x;
    for (; i < n; i += stride) counts[i] = 0;
}

__global__ void count_kernel(const int* __restrict__ dst, int* __restrict__ counts, int e) {
    int i = blockIdx.x * blockDim.x + threadIdx.x;
    int stride = gridDim.x * blockDim.x;
    for (; i < e; i += stride) atomicAdd(&counts[dst[i]], 1);
}

__global__ void dinv_kernel(const int* __restrict__ counts, float* __restrict__ dinv, int n) {
    int i = blockIdx.x * blockDim.x + threadIdx.x;
    int stride = gridDim.x * blockDim.x;
    for (; i < n; i += stride) dinv[i] = rsqrtf((float)(counts[i] + 1));
}

// --- 3-kernel exclusive scan over counts -> offsets -------------------------
__global__ void scan_partial(const int* __restrict__ counts, int* __restrict__ local,
                             int* __restrict__ bsums, int n) {
    __shared__ int ld[1024];
    __shared__ int ts[256];
    const int t = threadIdx.x;
    const int base = blockIdx.x * 1024;
    for (int j = t; j < 1024; j += 256) ld[j] = (base + j < n) ? counts[base + j] : 0;
    __syncthreads();
    int a0 = ld[4*t], a1 = ld[4*t+1], a2 = ld[4*t+2], a3 = ld[4*t+3];
    int sum = a0 + a1 + a2 + a3;
    ts[t] = sum;
    for (int off = 1; off < 256; off <<= 1) {
        __syncthreads();
        int v = (t >= off) ? ts[t - off] : 0;
        __syncthreads();
        ts[t] += v;
    }
    __syncthreads();
    int excl = ts[t] - sum;
    if (base + 4*t + 0 < n) local[base + 4*t + 0] = excl;
    if (base + 4*t + 1 < n) local[base + 4*t + 1] = excl + a0;
    if (base + 4*t + 2 < n) local[base + 4*t + 2] = excl + a0 + a1;
    if (base + 4*t + 3 < n) local[base + 4*t + 3] = excl + a0 + a1 + a2;
    if (t == 255) bsums[blockIdx.x] = ts[255];
}

__global__ void scan_bsums(int* __restrict__ bsums, int nb) {
    __shared__ int ts[256];
    const int t = threadIdx.x;
    int v = (t < nb) ? bsums[t] : 0;
    ts[t] = v;
    for (int off = 1; off < 256; off <<= 1) {
        __syncthreads();
        int u = (t >= off) ? ts[t - off] : 0;
        __syncthreads();
        ts[t] += u;
    }
    __syncthreads();
    if (t < nb) bsums[t] = ts[t] - v;
}

__global__ void scan_add(int* __restrict__ offs, const int* __restrict__ bsums, int n, int e_total) {
    int i = blockIdx.x * blockDim.x + threadIdx.x;
    int stride = gridDim.x * blockDim.x;
    for (; i < n; i += stride) offs[i] += bsums[i >> 10];
    if (blockIdx.x == 0 && threadIdx.x == 0) offs[n] = e_total;
}

__global__ void gcur_init(const int* __restrict__ offs, int* __restrict__ gcur,
                          int nb, int n) {
    int b = blockIdx.x * blockDim.x + threadIdx.x;
    if (b < nb) gcur[b] = offs[min(b << 9, n)];
}

// --- pass A: LDS-staged binning into exact per-window bucket regions --------
__global__ __launch_bounds__(256)
void binA_kernel(const int* __restrict__ src, const int* __restrict__ dst,
                 int* __restrict__ gcur, int* __restrict__ tmp, int e, int nb) {
    __shared__ int lbuf[PA_NB * PA_CAP];   // 50176 B
    __shared__ int cnt[PA_NB];
    __shared__ int gbase[PA_NB];
    const int tid = threadIdx.x;
    for (int b = tid; b < nb; b += 256) cnt[b] = 0;
    __syncthreads();

    const int per = (e + gridDim.x - 1) / gridDim.x;
    const int i0 = blockIdx.x * per;
    const int i1 = min(i0 + per, e);
    for (int i = i0 + tid; i < i1; i += 256) {
        int d = dst[i];
        int s = src[i];
        int b = d >> 9;
        int rec = ((d & 511) << 17) | s;
        int p = atomicAdd(&cnt[b], 1);
        if (p < PA_CAP) lbuf[b * PA_CAP + p] = rec;
        else tmp[atomicAdd(&gcur[b], 1)] = rec;   // rare overflow, still correct
    }
    __syncthreads();
    if (tid < nb) {
        int lvl = min(cnt[tid], PA_CAP);
        cnt[tid] = lvl;
        gbase[tid] = lvl ? atomicAdd(&gcur[tid], lvl) : 0;
    }
    __syncthreads();
    for (int bb = 0; bb < nb; bb += 4) {
        int b = bb + (tid >> 6);
        if (b < nb) {
            int lvl = cnt[b];
            int l = tid & 63;
            if (l < lvl) tmp[gbase[b] + l] = lbuf[b * PA_CAP + l];
        }
    }
}

// --- pass B: per-window LDS counting sort -> final CSR (coalesced write) ----
__global__ __launch_bounds__(256)
void sortB_kernel(const int* __restrict__ tmp, const int* __restrict__ offs,
                  int* __restrict__ csr, int n) {
    __shared__ int lcsr[PB_CAP];           // 40 KB
    __shared__ int cur[512];
    const int w = blockIdx.x;
    const int tid = threadIdx.x;
    const int node0 = w << 9;
    const int nloc = min(512, n - node0);
    const int base = offs[node0];
    const int end  = offs[min(node0 + 512, n)];
    for (int j = tid; j < nloc; j += 256) cur[j] = offs[node0 + j] - base;
    __syncthreads();
    for (int i = base + tid; i < end; i += 256) {
        int rec = tmp[i];
        int dl = (rec >> 17) & 511;
        int s = rec & 0x1FFFF;
        int p = atomicAdd(&cur[dl], 1);
        if (p < PB_CAP) lcsr[p] = s;
        else csr[base + p] = s;
    }
    __syncthreads();
    const int lim = min(end - base, PB_CAP);
    for (int i = tid; i < lim; i += 256) csr[base + i] = lcsr[i];
}

// --- pack W (f32 [128][DOUT]) into bf16 B-fragment order --------------------
template<int DOUT>
__global__ void packW_kernel(const float* __restrict__ W, ushort* __restrict__ Wf) {
    int idx = blockIdx.x * blockDim.x + threadIdx.x;   // 128*DOUT total
    if (idx >= 128 * DOUT) return;
    int k = idx / DOUT, col = idx % DOUT;
    int c = col >> 4, lcol = col & 15;
    int t = k >> 5, u = (k >> 3) & 3, j = k & 7;
    int lane = u * 16 + lcol;
    Wf[(size_t)(((c * 4 + t) * 64 + lane) * 8 + j)] = f2bf(W[idx]);
}

// --- matmul1 via MFMA: xws1[n x 128] (bf16) = dinv[r] * (x @ W1) ------------
__global__ __launch_bounds__(256)
void mfma1_kernel(const float* __restrict__ x, const ushort* __restrict__ W1f,
                  const float* __restrict__ dinv, ushort* __restrict__ outb, int n) {
    __shared__ ushort bsm[16384];                      // 32 KB, frag order
    const int tid = threadIdx.x;
    #pragma unroll
    for (int j = 0; j < 8; ++j)
        ((uint4*)bsm)[tid + j * 256] = ((const uint4*)W1f)[tid + j * 256];

    const int w = tid >> 6;
    const int lane = tid & 63;
    const int r = lane & 15;
    const int u = lane >> 4;
    const int row0 = blockIdx.x * 64 + w * 16;
    int arow = row0 + r; if (arow >= n) arow = n - 1;

    bf16x8 afr[4];
    #pragma unroll
    for (int t = 0; t < 4; ++t) {
        const float* px = &x[(size_t)arow * 128 + t * 32 + u * 8];
        f32x4 v0 = *(const f32x4*)px;
        f32x4 v1 = *(const f32x4*)(px + 4);
        bf16x8 a;
        a[0] = (short)f2bf(v0[0]); a[1] = (short)f2bf(v0[1]);
        a[2] = (short)f2bf(v0[2]); a[3] = (short)f2bf(v0[3]);
        a[4] = (short)f2bf(v1[0]); a[5] = (short)f2bf(v1[1]);
        a[6] = (short)f2bf(v1[2]); a[7] = (short)f2bf(v1[3]);
        afr[t] = a;
    }
    __syncthreads();

    f32x4 acc[8];
    #pragma unroll
    for (int c = 0; c < 8; ++c) acc[c] = (f32x4){0.f, 0.f, 0.f, 0.f};

    #pragma unroll
    for (int c = 0; c < 8; ++c) {
        #pragma unroll
        for (int t = 0; t < 4; ++t) {
            bf16x8 b = *(const bf16x8*)&bsm[(size_t)(((c * 4 + t) * 64 + lane) * 8)];
            acc[c] = __builtin_amdgcn_mfma_f32_16x16x32_bf16(afr[t], b, acc[c], 0, 0, 0);
        }
    }

    // D: col = lane&15 (=r), row = row0 + 4u + reg. Scale rows by dinv[row].
    const int rb = row0 + u * 4;
    f32x4 d4 = *(const f32x4*)&dinv[(rb + 3 < n) ? rb : 0];
    #pragma unroll
    for (int c = 0; c < 8; ++c) {
        #pragma unroll
        for (int rr = 0; rr < 4; ++rr) {
            int row = rb + rr;
            if (row < n) outb[(size_t)row * 128 + c * 16 + r] = f2bf(acc[c][rr] * d4[rr]);
        }
    }
}

// --- matmul2 via MFMA: xw2s[n x 32] (bf16) = dinv[r] * (hb @ W2) ------------
__global__ __launch_bounds__(256)
void mfma2_kernel(const ushort* __restrict__ hb, const ushort* __restrict__ W2f,
                  const float* __restrict__ dinv, ushort* __restrict__ outb, int n) {
    __shared__ ushort bsm[4096];                       // 8 KB
    const int tid = threadIdx.x;
    #pragma unroll
    for (int j = 0; j < 2; ++j)
        ((uint4*)bsm)[tid + j * 256] = ((const uint4*)W2f)[tid + j * 256];

    const int w = tid >> 6;
    const int lane = tid & 63;
    const int r = lane & 15;
    const int u = lane >> 4;
    const int row0 = blockIdx.x * 64 + w * 16;
    int arow = row0 + r; if (arow >= n) arow = n - 1;

    bf16x8 afr[4];
    #pragma unroll
    for (int t = 0; t < 4; ++t)
        afr[t] = *(const bf16x8*)&hb[(size_t)arow * 128 + t * 32 + u * 8];
    __syncthreads();

    f32x4 acc[2];
    acc[0] = (f32x4){0.f, 0.f, 0.f, 0.f};
    acc[1] = (f32x4){0.f, 0.f, 0.f, 0.f};
    #pragma unroll
    for (int c = 0; c < 2; ++c) {
        #pragma unroll
        for (int t = 0; t < 4; ++t) {
            bf16x8 b = *(const bf16x8*)&bsm[(size_t)(((c * 4 + t) * 64 + lane) * 8)];
            acc[c] = __builtin_amdgcn_mfma_f32_16x16x32_bf16(afr[t], b, acc[c], 0, 0, 0);
        }
    }

    const int rb = row0 + u * 4;
    f32x4 d4 = *(const f32x4*)&dinv[(rb + 3 < n) ? rb : 0];
    #pragma unroll
    for (int c = 0; c < 2; ++c) {
        #pragma unroll
        for (int rr = 0; rr < 4; ++rr) {
            int row = rb + rr;
            if (row < n) outb[(size_t)row * 32 + c * 16 + r] = f2bf(acc[c][rr] * d4[rr]);
        }
    }
}

// --- aggregation, D=128 over pre-scaled bf16 rows ---------------------------
// h[d] = relu(dinv[d] * (sum_{s in N(d)} xws[s] + xws[d]) + b1), stored bf16.
__device__ inline void bf2_add(uint u, float& a0, float& a1) {
    a0 += __uint_as_float(u << 16);
    a1 += __uint_as_float(u & 0xffff0000u);
}

__global__ __launch_bounds__(256)
void agg128_kernel(const ushort* __restrict__ xwb, const int* __restrict__ offs,
                   const int* __restrict__ csr, const float* __restrict__ dinv,
                   const float* __restrict__ bias, ushort* __restrict__ outb, int n) {
    const int w = threadIdx.x >> 6;
    const int i = blockIdx.x * 4 + w;
    if (i >= n) return;
    const int lane = threadIdx.x & 63;
    const int g = lane >> 4;
    const int q = lane & 15;

    float acc[8] = {};
    const int e0 = offs[i], e1 = offs[i + 1];
    int e = e0 + g;
    for (; e + 4 < e1; e += 8) {
        int s0 = csr[e];
        int s1 = csr[e + 4];
        uint4 u0 = *(const uint4*)&xwb[(size_t)s0 * 128 + q * 8];
        uint4 u1 = *(const uint4*)&xwb[(size_t)s1 * 128 + q * 8];
        bf2_add(u0.x, acc[0], acc[1]);
        bf2_add(u0.y, acc[2], acc[3]);
        bf2_add(u0.z, acc[4], acc[5]);
        bf2_add(u0.w, acc[6], acc[7]);
        bf2_add(u1.x, acc[0], acc[1]);
        bf2_add(u1.y, acc[2], acc[3]);
        bf2_add(u1.z, acc[4], acc[5]);
        bf2_add(u1.w, acc[6], acc[7]);
    }
    if (e < e1) {
        int s0 = csr[e];
        uint4 u = *(const uint4*)&xwb[(size_t)s0 * 128 + q * 8];
        bf2_add(u.x, acc[0], acc[1]);
        bf2_add(u.y, acc[2], acc[3]);
        bf2_add(u.z, acc[4], acc[5]);
        bf2_add(u.w, acc[6], acc[7]);
    }
    #pragma unroll
    for (int j = 0; j < 8; ++j) {
        acc[j] += __shfl_xor(acc[j], 16, 64);
        acc[j] += __shfl_xor(acc[j], 32, 64);
    }

    if (g == 0) {
        const float di = dinv[i];
        uint4 su = *(const uint4*)&xwb[(size_t)i * 128 + q * 8];
        bf2_add(su.x, acc[0], acc[1]);
        bf2_add(su.y, acc[2], acc[3]);
        bf2_add(su.z, acc[4], acc[5]);
        bf2_add(su.w, acc[6], acc[7]);
        const float4 b0 = *(const float4*)&bias[q * 8];
        const float4 b1 = *(const float4*)&bias[q * 8 + 4];
        ushort us[8];
        us[0] = f2bf(fmaxf(acc[0] * di + b0.x, 0.f));
        us[1] = f2bf(fmaxf(acc[1] * di + b0.y, 0.f));
        us[2] = f2bf(fmaxf(acc[2] * di + b0.z, 0.f));
        us[3] = f2bf(fmaxf(acc[3] * di + b0.w, 0.f));
        us[4] = f2bf(fmaxf(acc[4] * di + b1.x, 0.f));
        us[5] = f2bf(fmaxf(acc[5] * di + b1.y, 0.f));
        us[6] = f2bf(fmaxf(acc[6] * di + b1.z, 0.f));
        us[7] = f2bf(fmaxf(acc[7] * di + b1.w, 0.f));
        *(uint4*)&outb[(size_t)i * 128 + q * 8] = *(const uint4*)us;
    }
}

// --- aggregation, D=32 over pre-scaled bf16 rows (f32 out) ------------------
__global__ __launch_bounds__(256)
void agg32_kernel(const ushort* __restrict__ xwb, const int* __restrict__ offs,
                  const int* __restrict__ csr, const float* __restrict__ dinv,
                  const float* __restrict__ bias, float* __restrict__ out, int n) {
    const int w = threadIdx.x >> 6;
    const int i = blockIdx.x * 4 + w;
    if (i >= n) return;
    const int lane = threadIdx.x & 63;
    const int g = lane >> 3;
    const int q = lane & 7;

    float acc[4] = {};
    const int e0 = offs[i], e1 = offs[i + 1];
    int e = e0 + g;
    for (; e + 8 < e1; e += 16) {
        int s0 = csr[e];
        int s1 = csr[e + 8];
        uint2 u0 = *(const uint2*)&xwb[(size_t)s0 * 32 + q * 4];
        uint2 u1 = *(const uint2*)&xwb[(size_t)s1 * 32 + q * 4];
        bf2_add(u0.x, acc[0], acc[1]);
        bf2_add(u0.y, acc[2], acc[3]);
        bf2_add(u1.x, acc[0], acc[1]);
        bf2_add(u1.y, acc[2], acc[3]);
    }
    if (e < e1) {
        int s0 = csr[e];
        uint2 u = *(const uint2*)&xwb[(size_t)s0 * 32 + q * 4];
        bf2_add(u.x, acc[0], acc[1]);
        bf2_add(u.y, acc[2], acc[3]);
    }
    #pragma unroll
    for (int j = 0; j < 4; ++j) {
        acc[j] += __shfl_xor(acc[j], 8, 64);
        acc[j] += __shfl_xor(acc[j], 16, 64);
        acc[j] += __shfl_xor(acc[j], 32, 64);
    }

    if (g == 0) {
        const float di = dinv[i];
        uint2 su = *(const uint2*)&xwb[(size_t)i * 32 + q * 4];
        bf2_add(su.x, acc[0], acc[1]);
        bf2_add(su.y, acc[2], acc[3]);
        const float4 b = *(const float4*)&bias[q * 4];
        float4 r;
        r.x = acc[0] * di + b.x;
        r.y = acc[1] * di + b.y;
        r.z = acc[2] * di + b.z;
        r.w = acc[3] * di + b.w;
        *(float4*)&out[(size_t)i * 32 + q * 4] = r;
    }
}

extern "C" void kernel_launch(void* const* d_in, const int* in_sizes, int n_in,
                              void* d_out, int out_size, void* d_ws, size_t ws_size,
                              hipStream_t stream) {
    const int n = in_sizes[0] / KDIM;      // 100000
    const int e = in_sizes[1] / 2;         // 1600000

    const float* x  = (const float*)d_in[0];
    const int*   ei = (const int*)d_in[1];
    const int*   src = ei;
    const int*   dst = ei + e;
    const float* W1 = (const float*)d_in[2];
    const float* b1 = (const float*)d_in[3];
    const float* W2 = (const float*)d_in[4];
    const float* b2 = (const float*)d_in[5];
    float* out = (float*)d_out;

    // workspace carve (256B aligned)
    char* p = (char*)d_ws;
    auto alloc = [&](size_t bytes) { char* q = p; p += (bytes + 255) & ~(size_t)255; return q; };
    const int nwin = (n + 511) >> 9;                   // 196 node-windows
    float*  dinv   = (float*)alloc((size_t)n * 4);
    int*    counts = (int*)  alloc((size_t)n * 4);
    int*    offs   = (int*)  alloc((size_t)(n + 1) * 4);
    int*    bsums  = (int*)  alloc(1024 * 4);
    int*    gcur   = (int*)  alloc((size_t)nwin * 4);
    int*    csr    = (int*)  alloc((size_t)e * 4);
    ushort* W1f    = (ushort*)alloc((size_t)128 * 128 * 2);
    ushort* W2f    = (ushort*)alloc((size_t)128 * 32 * 2);
    ushort* xws1   = (ushort*)alloc((size_t)n * 128 * 2);
    ushort* hb     = (ushort*)alloc((size_t)n * 128 * 2);
    ushort* xw2s   = (ushort*)alloc((size_t)n * 32 * 2);
    int*    tmp    = (int*)hb;             // binned records alias hb (free until agg128)

    const int nb_scan = (n + 1023) / 1024;

    init_counts<<<256, 256, 0, stream>>>(counts, n);
    count_kernel<<<2048, 256, 0, stream>>>(dst, counts, e);
    dinv_kernel<<<(n + 255) / 256, 256, 0, stream>>>(counts, dinv, n);
    scan_partial<<<nb_scan, 256, 0, stream>>>(counts, offs, bsums, n);
    scan_bsums<<<1, 256, 0, stream>>>(bsums, nb_scan);
    scan_add<<<512, 256, 0, stream>>>(offs, bsums, n, e);
    gcur_init<<<(nwin + 255) / 256, 256, 0, stream>>>(offs, gcur, nwin, n);
    binA_kernel<<<256, 256, 0, stream>>>(src, dst, gcur, tmp, e, nwin);
    sortB_kernel<<<nwin, 256, 0, stream>>>(tmp, offs, csr, n);
    packW_kernel<128><<<64, 256, 0, stream>>>(W1, W1f);
    packW_kernel<32><<<16, 256, 0, stream>>>(W2, W2f);

    // layer 1: xws1 = bf16(dinv*(x@W1)) ; hb = bf16(relu(dinv*sum + b1))
    mfma1_kernel<<<(n + 63) / 64, 256, 0, stream>>>(x, W1f, dinv, xws1, n);
    agg128_kernel<<<(n + 3) / 4, 256, 0, stream>>>(xws1, offs, csr, dinv, b1, hb, n);

    // layer 2: xw2s = bf16(dinv*(hb@W2)) ; out = dinv*sum + b2
    mfma2_kernel<<<(n + 63) / 64, 256, 0, stream>>>(hb, W2f, dinv, xw2s, n);
    agg32_kernel<<<(n + 3) / 4, 256, 0, stream>>>(xw2s, offs, csr, dinv, b2, out, n);
}

// Round 9
// 197.716 us; speedup vs baseline: 1.8960x; 1.2885x over previous
//
#include <hip/hip_runtime.h>

// ---------------------------------------------------------------------------
// 2-layer GCN: z = A_hat (relu(A_hat (X W1) + b1)) W2 + b2
// R9: no per-node global atomics anywhere. CSR build:
//   wincount: LDS histogram over 196 dst-windows -> ~50K global atomics total
//   winscan:  1-WG scan -> winbase + gcur
//   binA:     LDS-staged binning into window regions (R7, unchanged)
//   sortB:    per-window LDS histogram + scan + counting sort; emits offs,
//             dinv, and sorted CSR with fully coalesced writes.
// (R8's count_kernel: 1.6M global atomics over 400KB -> 50MB of L2-line
//  ping-pong between XCDs, 66us. Deleted.)
// dinv[src] folded into transformed rows; h/xw2 bf16; both matmuls MFMA.
// ---------------------------------------------------------------------------

#define KDIM 128
#define PA_NB 196      // max node-windows: ceil(100352/512)
#define PA_CAP 64      // records per LDS bin in binA
#define PB_CAP 10240   // LDS records per window sort (avg 8192, 22 sigma)

typedef unsigned int uint;
typedef unsigned short ushort;
typedef __attribute__((ext_vector_type(8))) short bf16x8;
typedef __attribute__((ext_vector_type(4))) float f32x4;

__device__ inline ushort f2bf(float f) {              // RNE f32 -> bf16
    uint u = __float_as_uint(f);
    return (ushort)((u + 0x7fffu + ((u >> 16) & 1u)) >> 16);
}

// --- window-total histogram (LDS-staged) ------------------------------------
__global__ void initw_kernel(int* wcnt, int nwin) {
    int b = threadIdx.x;
    if (b < nwin) wcnt[b] = 0;
}

__global__ __launch_bounds__(256)
void wincount_kernel(const int* __restrict__ dst, int* __restrict__ wcnt, int e, int nwin) {
    __shared__ int lcnt[PA_NB];
    const int tid = threadIdx.x;
    for (int b = tid; b < nwin; b += 256) lcnt[b] = 0;
    __syncthreads();
    int i = blockIdx.x * blockDim.x + tid;
    const int stride = gridDim.x * blockDim.x;
    for (; i < e; i += stride) atomicAdd(&lcnt[dst[i] >> 9], 1);
    __syncthreads();
    for (int b = tid; b < nwin; b += 256) {
        int v = lcnt[b];
        if (v) atomicAdd(&wcnt[b], v);
    }
}

// --- 1-WG scan of window totals -> winbase[nwin+1], gcur --------------------
__global__ __launch_bounds__(256)
void winscan_kernel(const int* __restrict__ wcnt, int* __restrict__ winbase,
                    int* __restrict__ gcur, int nwin, int e) {
    __shared__ int ts[256];
    const int t = threadIdx.x;
    int v = (t < nwin) ? wcnt[t] : 0;
    ts[t] = v;
    for (int off = 1; off < 256; off <<= 1) {
        __syncthreads();
        int u = (t >= off) ? ts[t - off] : 0;
        __syncthreads();
        ts[t] += u;
    }
    __syncthreads();
    if (t < nwin) {
        int base = ts[t] - v;
        winbase[t] = base;
        gcur[t] = base;
    }
    if (t == 0) winbase[nwin] = e;
}

// --- pass A: LDS-staged binning into window regions (R7) --------------------
__global__ __launch_bounds__(256)
void binA_kernel(const int* __restrict__ src, const int* __restrict__ dst,
                 int* __restrict__ gcur, int* __restrict__ tmp, int e, int nb) {
    __shared__ int lbuf[PA_NB * PA_CAP];   // 50176 B
    __shared__ int cnt[PA_NB];
    __shared__ int gbase[PA_NB];
    const int tid = threadIdx.x;
    for (int b = tid; b < nb; b += 256) cnt[b] = 0;
    __syncthreads();

    const int per = (e + gridDim.x - 1) / gridDim.x;
    const int i0 = blockIdx.x * per;
    const int i1 = min(i0 + per, e);
    for (int i = i0 + tid; i < i1; i += 256) {
        int d = dst[i];
        int s = src[i];
        int b = d >> 9;
        int rec = ((d & 511) << 17) | s;
        int p = atomicAdd(&cnt[b], 1);
        if (p < PA_CAP) lbuf[b * PA_CAP + p] = rec;
        else tmp[atomicAdd(&gcur[b], 1)] = rec;   // rare overflow, still correct
    }
    __syncthreads();
    if (tid < nb) {
        int lvl = min(cnt[tid], PA_CAP);
        cnt[tid] = lvl;
        gbase[tid] = lvl ? atomicAdd(&gcur[tid], lvl) : 0;
    }
    __syncthreads();
    for (int bb = 0; bb < nb; bb += 4) {
        int b = bb + (tid >> 6);
        if (b < nb) {
            int lvl = cnt[b];
            int l = tid & 63;
            if (l < lvl) tmp[gbase[b] + l] = lbuf[b * PA_CAP + l];
        }
    }
}

// --- pass B: per-window histogram + scan + counting sort --------------------
// Emits offs[node0..], dinv[node0..] (coalesced), sorted CSR.
__global__ __launch_bounds__(256)
void sortB_kernel(const int* __restrict__ tmp, const int* __restrict__ winbase,
                  int* __restrict__ offs, float* __restrict__ dinv,
                  int* __restrict__ csr, int n, int e) {
    __shared__ int lcsr[PB_CAP];           // 40 KB
    __shared__ int cnt[512];               // histogram, then reused as cursors
    __shared__ int ts[256];
    const int w = blockIdx.x;
    const int tid = threadIdx.x;
    const int node0 = w << 9;
    const int nloc = min(512, n - node0);
    const int base = winbase[w];
    const int end  = winbase[w + 1];

    for (int j = tid; j < 512; j += 256) cnt[j] = 0;
    __syncthreads();
    for (int i = base + tid; i < end; i += 256)
        atomicAdd(&cnt[(tmp[i] >> 17) & 511], 1);
    __syncthreads();

    // exclusive scan over 512 (2 elems/thread)
    int a0 = cnt[2 * tid], a1 = cnt[2 * tid + 1];
    int sum = a0 + a1;
    ts[tid] = sum;
    for (int off = 1; off < 256; off <<= 1) {
        __syncthreads();
        int v = (tid >= off) ? ts[tid - off] : 0;
        __syncthreads();
        ts[tid] += v;
    }
    __syncthreads();
    const int ex = ts[tid] - sum;
    // emit offs + dinv (coalesced within window), reset cursors
    if (2 * tid < nloc) {
        offs[node0 + 2 * tid] = base + ex;
        dinv[node0 + 2 * tid] = rsqrtf((float)(a0 + 1));
    }
    if (2 * tid + 1 < nloc) {
        offs[node0 + 2 * tid + 1] = base + ex + a0;
        dinv[node0 + 2 * tid + 1] = rsqrtf((float)(a1 + 1));
    }
    cnt[2 * tid] = ex;
    cnt[2 * tid + 1] = ex + a0;
    if (w == gridDim.x - 1 && tid == 0) offs[n] = e;
    __syncthreads();

    // counting sort into LDS, then coalesced CSR copy
    for (int i = base + tid; i < end; i += 256) {
        int rec = tmp[i];
        int dl = (rec >> 17) & 511;
        int s = rec & 0x1FFFF;
        int p = atomicAdd(&cnt[dl], 1);
        if (p < PB_CAP) lcsr[p] = s;
        else csr[base + p] = s;            // pathological overflow fallback
    }
    __syncthreads();
    const int lim = min(end - base, PB_CAP);
    for (int i = tid; i < lim; i += 256) csr[base + i] = lcsr[i];
}

// --- pack W (f32 [128][DOUT]) into bf16 B-fragment order --------------------
template<int DOUT>
__global__ void packW_kernel(const float* __restrict__ W, ushort* __restrict__ Wf) {
    int idx = blockIdx.x * blockDim.x + threadIdx.x;   // 128*DOUT total
    if (idx >= 128 * DOUT) return;
    int k = idx / DOUT, col = idx % DOUT;
    int c = col >> 4, lcol = col & 15;
    int t = k >> 5, u = (k >> 3) & 3, j = k & 7;
    int lane = u * 16 + lcol;
    Wf[(size_t)(((c * 4 + t) * 64 + lane) * 8 + j)] = f2bf(W[idx]);
}

// --- matmul1 via MFMA: xws1[n x 128] (bf16) = dinv[r] * (x @ W1) ------------
__global__ __launch_bounds__(256)
void mfma1_kernel(const float* __restrict__ x, const ushort* __restrict__ W1f,
                  const float* __restrict__ dinv, ushort* __restrict__ outb, int n) {
    __shared__ ushort bsm[16384];                      // 32 KB, frag order
    const int tid = threadIdx.x;
    #pragma unroll
    for (int j = 0; j < 8; ++j)
        ((uint4*)bsm)[tid + j * 256] = ((const uint4*)W1f)[tid + j * 256];

    const int w = tid >> 6;
    const int lane = tid & 63;
    const int r = lane & 15;
    const int u = lane >> 4;
    const int row0 = blockIdx.x * 64 + w * 16;
    int arow = row0 + r; if (arow >= n) arow = n - 1;

    bf16x8 afr[4];
    #pragma unroll
    for (int t = 0; t < 4; ++t) {
        const float* px = &x[(size_t)arow * 128 + t * 32 + u * 8];
        f32x4 v0 = *(const f32x4*)px;
        f32x4 v1 = *(const f32x4*)(px + 4);
        bf16x8 a;
        a[0] = (short)f2bf(v0[0]); a[1] = (short)f2bf(v0[1]);
        a[2] = (short)f2bf(v0[2]); a[3] = (short)f2bf(v0[3]);
        a[4] = (short)f2bf(v1[0]); a[5] = (short)f2bf(v1[1]);
        a[6] = (short)f2bf(v1[2]); a[7] = (short)f2bf(v1[3]);
        afr[t] = a;
    }
    __syncthreads();

    f32x4 acc[8];
    #pragma unroll
    for (int c = 0; c < 8; ++c) acc[c] = (f32x4){0.f, 0.f, 0.f, 0.f};

    #pragma unroll
    for (int c = 0; c < 8; ++c) {
        #pragma unroll
        for (int t = 0; t < 4; ++t) {
            bf16x8 b = *(const bf16x8*)&bsm[(size_t)(((c * 4 + t) * 64 + lane) * 8)];
            acc[c] = __builtin_amdgcn_mfma_f32_16x16x32_bf16(afr[t], b, acc[c], 0, 0, 0);
        }
    }

    const int rb = row0 + u * 4;
    f32x4 d4 = *(const f32x4*)&dinv[(rb + 3 < n) ? rb : 0];
    #pragma unroll
    for (int c = 0; c < 8; ++c) {
        #pragma unroll
        for (int rr = 0; rr < 4; ++rr) {
            int row = rb + rr;
            if (row < n) outb[(size_t)row * 128 + c * 16 + r] = f2bf(acc[c][rr] * d4[rr]);
        }
    }
}

// --- matmul2 via MFMA: xw2s[n x 32] (bf16) = dinv[r] * (hb @ W2) ------------
__global__ __launch_bounds__(256)
void mfma2_kernel(const ushort* __restrict__ hb, const ushort* __restrict__ W2f,
                  const float* __restrict__ dinv, ushort* __restrict__ outb, int n) {
    __shared__ ushort bsm[4096];                       // 8 KB
    const int tid = threadIdx.x;
    #pragma unroll
    for (int j = 0; j < 2; ++j)
        ((uint4*)bsm)[tid + j * 256] = ((const uint4*)W2f)[tid + j * 256];

    const int w = tid >> 6;
    const int lane = tid & 63;
    const int r = lane & 15;
    const int u = lane >> 4;
    const int row0 = blockIdx.x * 64 + w * 16;
    int arow = row0 + r; if (arow >= n) arow = n - 1;

    bf16x8 afr[4];
    #pragma unroll
    for (int t = 0; t < 4; ++t)
        afr[t] = *(const bf16x8*)&hb[(size_t)arow * 128 + t * 32 + u * 8];
    __syncthreads();

    f32x4 acc[2];
    acc[0] = (f32x4){0.f, 0.f, 0.f, 0.f};
    acc[1] = (f32x4){0.f, 0.f, 0.f, 0.f};
    #pragma unroll
    for (int c = 0; c < 2; ++c) {
        #pragma unroll
        for (int t = 0; t < 4; ++t) {
            bf16x8 b = *(const bf16x8*)&bsm[(size_t)(((c * 4 + t) * 64 + lane) * 8)];
            acc[c] = __builtin_amdgcn_mfma_f32_16x16x32_bf16(afr[t], b, acc[c], 0, 0, 0);
        }
    }

    const int rb = row0 + u * 4;
    f32x4 d4 = *(const f32x4*)&dinv[(rb + 3 < n) ? rb : 0];
    #pragma unroll
    for (int c = 0; c < 2; ++c) {
        #pragma unroll
        for (int rr = 0; rr < 4; ++rr) {
            int row = rb + rr;
            if (row < n) outb[(size_t)row * 32 + c * 16 + r] = f2bf(acc[c][rr] * d4[rr]);
        }
    }
}

// --- aggregation, D=128 over pre-scaled bf16 rows ---------------------------
__device__ inline void bf2_add(uint u, float& a0, float& a1) {
    a0 += __uint_as_float(u << 16);
    a1 += __uint_as_float(u & 0xffff0000u);
}

__global__ __launch_bounds__(256)
void agg128_kernel(const ushort* __restrict__ xwb, const int* __restrict__ offs,
                   const int* __restrict__ csr, const float* __restrict__ dinv,
                   const float* __restrict__ bias, ushort* __restrict__ outb, int n) {
    const int w = threadIdx.x >> 6;
    const int i = blockIdx.x * 4 + w;
    if (i >= n) return;
    const int lane = threadIdx.x & 63;
    const int g = lane >> 4;
    const int q = lane & 15;

    float acc[8] = {};
    const int e0 = offs[i], e1 = offs[i + 1];
    int e = e0 + g;
    for (; e + 4 < e1; e += 8) {
        int s0 = csr[e];
        int s1 = csr[e + 4];
        uint4 u0 = *(const uint4*)&xwb[(size_t)s0 * 128 + q * 8];
        uint4 u1 = *(const uint4*)&xwb[(size_t)s1 * 128 + q * 8];
        bf2_add(u0.x, acc[0], acc[1]);
        bf2_add(u0.y, acc[2], acc[3]);
        bf2_add(u0.z, acc[4], acc[5]);
        bf2_add(u0.w, acc[6], acc[7]);
        bf2_add(u1.x, acc[0], acc[1]);
        bf2_add(u1.y, acc[2], acc[3]);
        bf2_add(u1.z, acc[4], acc[5]);
        bf2_add(u1.w, acc[6], acc[7]);
    }
    if (e < e1) {
        int s0 = csr[e];
        uint4 u = *(const uint4*)&xwb[(size_t)s0 * 128 + q * 8];
        bf2_add(u.x, acc[0], acc[1]);
        bf2_add(u.y, acc[2], acc[3]);
        bf2_add(u.z, acc[4], acc[5]);
        bf2_add(u.w, acc[6], acc[7]);
    }
    #pragma unroll
    for (int j = 0; j < 8; ++j) {
        acc[j] += __shfl_xor(acc[j], 16, 64);
        acc[j] += __shfl_xor(acc[j], 32, 64);
    }

    if (g == 0) {
        const float di = dinv[i];
        uint4 su = *(const uint4*)&xwb[(size_t)i * 128 + q * 8];
        bf2_add(su.x, acc[0], acc[1]);
        bf2_add(su.y, acc[2], acc[3]);
        bf2_add(su.z, acc[4], acc[5]);
        bf2_add(su.w, acc[6], acc[7]);
        const float4 b0 = *(const float4*)&bias[q * 8];
        const float4 b1 = *(const float4*)&bias[q * 8 + 4];
        ushort us[8];
        us[0] = f2bf(fmaxf(acc[0] * di + b0.x, 0.f));
        us[1] = f2bf(fmaxf(acc[1] * di + b0.y, 0.f));
        us[2] = f2bf(fmaxf(acc[2] * di + b0.z, 0.f));
        us[3] = f2bf(fmaxf(acc[3] * di + b0.w, 0.f));
        us[4] = f2bf(fmaxf(acc[4] * di + b1.x, 0.f));
        us[5] = f2bf(fmaxf(acc[5] * di + b1.y, 0.f));
        us[6] = f2bf(fmaxf(acc[6] * di + b1.z, 0.f));
        us[7] = f2bf(fmaxf(acc[7] * di + b1.w, 0.f));
        *(uint4*)&outb[(size_t)i * 128 + q * 8] = *(const uint4*)us;
    }
}

// --- aggregation, D=32 over pre-scaled bf16 rows (f32 out) ------------------
__global__ __launch_bounds__(256)
void agg32_kernel(const ushort* __restrict__ xwb, const int* __restrict__ offs,
                  const int* __restrict__ csr, const float* __restrict__ dinv,
                  const float* __restrict__ bias, float* __restrict__ out, int n) {
    const int w = threadIdx.x >> 6;
    const int i = blockIdx.x * 4 + w;
    if (i >= n) return;
    const int lane = threadIdx.x & 63;
    const int g = lane >> 3;
    const int q = lane & 7;

    float acc[4] = {};
    const int e0 = offs[i], e1 = offs[i + 1];
    int e = e0 + g;
    for (; e + 8 < e1; e += 16) {
        int s0 = csr[e];
        int s1 = csr[e + 8];
        uint2 u0 = *(const uint2*)&xwb[(size_t)s0 * 32 + q * 4];
        uint2 u1 = *(const uint2*)&xwb[(size_t)s1 * 32 + q * 4];
        bf2_add(u0.x, acc[0], acc[1]);
        bf2_add(u0.y, acc[2], acc[3]);
        bf2_add(u1.x, acc[0], acc[1]);
        bf2_add(u1.y, acc[2], acc[3]);
    }
    if (e < e1) {
        int s0 = csr[e];
        uint2 u = *(const uint2*)&xwb[(size_t)s0 * 32 + q * 4];
        bf2_add(u.x, acc[0], acc[1]);
        bf2_add(u.y, acc[2], acc[3]);
    }
    #pragma unroll
    for (int j = 0; j < 4; ++j) {
        acc[j] += __shfl_xor(acc[j], 8, 64);
        acc[j] += __shfl_xor(acc[j], 16, 64);
        acc[j] += __shfl_xor(acc[j], 32, 64);
    }

    if (g == 0) {
        const float di = dinv[i];
        uint2 su = *(const uint2*)&xwb[(size_t)i * 32 + q * 4];
        bf2_add(su.x, acc[0], acc[1]);
        bf2_add(su.y, acc[2], acc[3]);
        const float4 b = *(const float4*)&bias[q * 4];
        float4 r;
        r.x = acc[0] * di + b.x;
        r.y = acc[1] * di + b.y;
        r.z = acc[2] * di + b.z;
        r.w = acc[3] * di + b.w;
        *(float4*)&out[(size_t)i * 32 + q * 4] = r;
    }
}

extern "C" void kernel_launch(void* const* d_in, const int* in_sizes, int n_in,
                              void* d_out, int out_size, void* d_ws, size_t ws_size,
                              hipStream_t stream) {
    const int n = in_sizes[0] / KDIM;      // 100000
    const int e = in_sizes[1] / 2;         // 1600000

    const float* x  = (const float*)d_in[0];
    const int*   ei = (const int*)d_in[1];
    const int*   src = ei;
    const int*   dst = ei + e;
    const float* W1 = (const float*)d_in[2];
    const float* b1 = (const float*)d_in[3];
    const float* W2 = (const float*)d_in[4];
    const float* b2 = (const float*)d_in[5];
    float* out = (float*)d_out;

    // workspace carve (256B aligned)
    char* p = (char*)d_ws;
    auto alloc = [&](size_t bytes) { char* q = p; p += (bytes + 255) & ~(size_t)255; return q; };
    const int nwin = (n + 511) >> 9;                   // 196 node-windows
    float*  dinv    = (float*)alloc((size_t)n * 4);
    int*    offs    = (int*)  alloc((size_t)(n + 1) * 4);
    int*    wcnt    = (int*)  alloc((size_t)nwin * 4);
    int*    winbase = (int*)  alloc((size_t)(nwin + 1) * 4);
    int*    gcur    = (int*)  alloc((size_t)nwin * 4);
    int*    csr     = (int*)  alloc((size_t)e * 4);
    ushort* W1f     = (ushort*)alloc((size_t)128 * 128 * 2);
    ushort* W2f     = (ushort*)alloc((size_t)128 * 32 * 2);
    ushort* xws1    = (ushort*)alloc((size_t)n * 128 * 2);
    ushort* hb      = (ushort*)alloc((size_t)n * 128 * 2);
    ushort* xw2s    = (ushort*)alloc((size_t)n * 32 * 2);
    int*    tmp     = (int*)hb;            // binned records alias hb (free until agg128)

    initw_kernel<<<1, 256, 0, stream>>>(wcnt, nwin);
    wincount_kernel<<<512, 256, 0, stream>>>(dst, wcnt, e, nwin);
    winscan_kernel<<<1, 256, 0, stream>>>(wcnt, winbase, gcur, nwin, e);
    binA_kernel<<<256, 256, 0, stream>>>(src, dst, gcur, tmp, e, nwin);
    sortB_kernel<<<nwin, 256, 0, stream>>>(tmp, winbase, offs, dinv, csr, n, e);
    packW_kernel<128><<<64, 256, 0, stream>>>(W1, W1f);
    packW_kernel<32><<<16, 256, 0, stream>>>(W2, W2f);

    // layer 1: xws1 = bf16(dinv*(x@W1)) ; hb = bf16(relu(dinv*sum + b1))
    mfma1_kernel<<<(n + 63) / 64, 256, 0, stream>>>(x, W1f, dinv, xws1, n);
    agg128_kernel<<<(n + 3) / 4, 256, 0, stream>>>(xws1, offs, csr, dinv, b1, hb, n);

    // layer 2: xw2s = bf16(dinv*(hb@W2)) ; out = dinv*sum + b2
    mfma2_kernel<<<(n + 63) / 64, 256, 0, stream>>>(hb, W2f, dinv, xw2s, n);
    agg32_kernel<<<(n + 3) / 4, 256, 0, stream>>>(xw2s, offs, csr, dinv, b2, out, n);
}